// Round 3
// baseline (1958.695 us; speedup 1.0000x reference)
//
#include <hip/hip_runtime.h>
#include <hip/hip_bf16.h>
#include <math.h>

// ---- problem constants ----
#define BATCH  2
#define S_TOK  2046
#define NCOND  2
#define SEQ    2048
#define DMODEL 512
#define DINNER 2048
#define NHEAD  8
#define DHEAD  64
#define NLAYER 6
#define VOCAB  512
#define MROWS  (BATCH*SEQ)   // 4096 rows

typedef unsigned short bf16u;
typedef __attribute__((ext_vector_type(8))) short s8frag;   // 8 bf16 (4 VGPRs)
typedef __attribute__((ext_vector_type(4))) float f4frag;   // 4 fp32 acc

__device__ __forceinline__ float b2f(bf16u u) {
  union { unsigned int i; float f; } v; v.i = ((unsigned int)u) << 16; return v.f;
}
__device__ __forceinline__ bf16u f2b(float f) {
  union { float f; unsigned int i; } v; v.f = f;
  unsigned int x = v.i;
  return (bf16u)((x + 0x7fffu + ((x >> 16) & 1u)) >> 16);
}
__device__ __forceinline__ unsigned int pack2(float a, float b) {
  return (unsigned int)f2b(a) | ((unsigned int)f2b(b) << 16);
}

// DPP row-rotate (within 16-lane row) — VALU-pipe lane exchange, not LDS.
// row_ror:N ctrl = 0x120+N. Rotate-accumulate x4 gives a full 16-lane reduce.
#define DPP_ROR(dst, src, N)                                              \
  dst = __int_as_float(__builtin_amdgcn_update_dpp(                       \
      0, __float_as_int(src), 0x120 + (N), 0xF, 0xF, true))

// ---------------------------------------------------------------------------
// All-layer weight transpose + bf16: dst[N][K] = src[K][N]. One launch.
// blocks: 6 layers x 768 (q64|k64|v64|o64|W1 256|W2 256) + 64 (fc) = 4672.
// ---------------------------------------------------------------------------
__global__ __launch_bounds__(256) void wt_all_kernel(
    const float* __restrict__ Wq, const float* __restrict__ Wk,
    const float* __restrict__ Wv, const float* __restrict__ Wo,
    const float* __restrict__ W1, const float* __restrict__ W2,
    const float* __restrict__ fcW,
    bf16u* __restrict__ qkvT, bf16u* __restrict__ oT,
    bf16u* __restrict__ w1T, bf16u* __restrict__ w2T, bf16u* __restrict__ fcT)
{
  int bid = blockIdx.x;
  const float* src; bf16u* dst; int N, K, kt, nt;
  if (bid < 6 * 768) {
    int L = bid / 768, t = bid - L * 768;
    if (t < 256) {
      int mat = t >> 6, tt = t & 63;
      const float* s4[4] = {Wq, Wk, Wv, Wo};
      src = s4[mat] + (size_t)L * DMODEL * DMODEL;
      dst = (mat < 3) ? (qkvT + (size_t)L * 786432 + (size_t)mat * 262144)
                      : (oT + (size_t)L * 262144);
      K = DMODEL; N = DMODEL; kt = tt >> 3; nt = tt & 7;
    } else if (t < 512) {
      int tt = t - 256;
      src = W1 + (size_t)L * DMODEL * DINNER; dst = w1T + (size_t)L * 1048576;
      K = DMODEL; N = DINNER; kt = tt >> 5; nt = tt & 31;
    } else {
      int tt = t - 512;
      src = W2 + (size_t)L * DINNER * DMODEL; dst = w2T + (size_t)L * 1048576;
      K = DINNER; N = DMODEL; kt = tt >> 3; nt = tt & 7;
    }
  } else {
    int tt = bid - 6 * 768;
    src = fcW; dst = fcT;
    K = DMODEL; N = VOCAB; kt = tt >> 3; nt = tt & 7;
  }
  __shared__ bf16u Ls[64][66];
  int tid = threadIdx.x;
  int c = tid & 63, r4 = tid >> 6;
#pragma unroll
  for (int i = 0; i < 16; i++) {
    int r = i * 4 + r4;
    Ls[r][c] = f2b(src[(size_t)(kt * 64 + r) * N + nt * 64 + c]);
  }
  __syncthreads();
#pragma unroll
  for (int i = 0; i < 16; i++) {
    int rr = i * 4 + r4;
    dst[(size_t)(nt * 64 + rr) * K + kt * 64 + c] = Ls[c][rr];
  }
}

// ---------------------------------------------------------------------------
// V transpose (bf16): vb[(b,i)][h*64+d] -> vbt[(b*8+h)*64+d][i]. 512 blocks.
// ---------------------------------------------------------------------------
__global__ __launch_bounds__(256) void vt_kernel(
    const bf16u* __restrict__ vb, bf16u* __restrict__ vbt)
{
  int bid = blockIdx.x;
  int b = bid >> 8, t = bid & 255;
  int it = t >> 3, h = t & 7;
  __shared__ bf16u Ls[64][66];
  int tid = threadIdx.x;
  int c = tid & 63, r4 = tid >> 6;
#pragma unroll
  for (int i = 0; i < 16; i++) {
    int r = i * 4 + r4;
    Ls[r][c] = vb[(size_t)(b * SEQ + it * 64 + r) * DMODEL + h * DHEAD + c];
  }
  __syncthreads();
#pragma unroll
  for (int i = 0; i < 16; i++) {
    int rr = i * 4 + r4;
    vbt[(size_t)((b * 8 + h) * DHEAD + rr) * SEQ + it * 64 + c] = Ls[c][rr];
  }
}

// ---------------------------------------------------------------------------
// MFMA GEMM, RB m-tiles/wave (4 -> 128x128, 2 -> 64x128).
// modes: 0 +bias->bf16 ; 1 +bias+Rb(bf16)->bf16 ; 2 relu(+bias)+chord->bf16 ;
//        3 +bias->fp32 ; 4 fused-QKV routing -> bf16 (3 slices)
// ---------------------------------------------------------------------------
template <int RB>
__global__ __launch_bounds__(256) void mgemm(
    const bf16u* __restrict__ A, const bf16u* __restrict__ Wt,
    const float* __restrict__ b0, const float* __restrict__ b1,
    const float* __restrict__ b2, const bf16u* __restrict__ Rb,
    float* __restrict__ Cf, bf16u* __restrict__ Cb,
    int M, int N, int K, int mode,
    const float* __restrict__ ttc, const float* __restrict__ ttcW,
    const float* __restrict__ ttcb)
{
  __shared__ bf16u Ab[RB * 32][40];
  __shared__ bf16u Bb[128][40];
  const int tid = threadIdx.x;
  const int lane = tid & 63, wave = tid >> 6;
  const int quad = lane >> 4, l16 = lane & 15;
  const int wm = wave >> 1, wn = wave & 1;
  const int row0 = blockIdx.x * (RB * 32), col0 = blockIdx.y * 128;

  f4frag acc[RB][4];
#pragma unroll
  for (int i = 0; i < RB; i++)
#pragma unroll
    for (int j = 0; j < 4; j++) acc[i][j] = (f4frag){0.f, 0.f, 0.f, 0.f};

  for (int k0 = 0; k0 < K; k0 += 32) {
    if (k0) __syncthreads();
    if constexpr (RB >= 2) {
#pragma unroll
      for (int i = 0; i < RB / 2; i++) {
        int c = tid + i * 256;
        int r = c >> 2, koff = (c & 3) * 8;
        *(uint4*)&Ab[r][koff] = *(const uint4*)&A[(size_t)(row0 + r) * K + k0 + koff];
      }
    } else {
      if (tid < 128) {
        int r = tid >> 2, koff = (tid & 3) * 8;
        *(uint4*)&Ab[r][koff] = *(const uint4*)&A[(size_t)(row0 + r) * K + k0 + koff];
      }
    }
#pragma unroll
    for (int i = 0; i < 2; i++) {
      int c = tid + i * 256;
      int r = c >> 2, koff = (c & 3) * 8;
      *(uint4*)&Bb[r][koff] = *(const uint4*)&Wt[(size_t)(col0 + r) * K + k0 + koff];
    }
    __syncthreads();
    s8frag af[RB], bfr[4];
#pragma unroll
    for (int t = 0; t < RB; t++)
      af[t] = *(const s8frag*)&Ab[wm * (RB * 16) + t * 16 + l16][quad * 8];
#pragma unroll
    for (int t = 0; t < 4; t++)
      bfr[t] = *(const s8frag*)&Bb[wn * 64 + t * 16 + l16][quad * 8];
#pragma unroll
    for (int mt = 0; mt < RB; mt++)
#pragma unroll
      for (int nt = 0; nt < 4; nt++)
        acc[mt][nt] = __builtin_amdgcn_mfma_f32_16x16x32_bf16(
            af[mt], bfr[nt], acc[mt][nt], 0, 0, 0);
  }

#pragma unroll
  for (int mt = 0; mt < RB; mt++) {
#pragma unroll
    for (int r = 0; r < 4; r++) {
      int m = row0 + wm * (RB * 16) + mt * 16 + quad * 4 + r;
      float tval = 0.f;
      if (mode == 2) {
        int bb = m >> 11, s = m & (SEQ - 1);
        int sp = (s < NCOND) ? 0 : (s - NCOND);
        tval = 8.0f - ttc[bb * S_TOK + sp];
      }
#pragma unroll
      for (int nt = 0; nt < 4; nt++) {
        int n = col0 + wn * 64 + nt * 16 + l16;
        if (mode == 4) {
          int sel = n >> 9, nn = n & 511;
          float bv = (sel == 0) ? b0[nn] : ((sel == 1) ? b1[nn] : b2[nn]);
          Cb[(size_t)sel * MROWS * DMODEL + (size_t)m * DMODEL + nn]
              = f2b(acc[mt][nt][r] + bv);
        } else {
          float v = acc[mt][nt][r] + b0[n];
          if (mode == 1)      v += b2f(Rb[(size_t)m * N + n]);
          else if (mode == 2) v = fmaxf(v, 0.f) + tval * ttcW[n] + ttcb[n];
          if (mode == 3) Cf[(size_t)m * N + n] = v;
          else           Cb[(size_t)m * N + n] = f2b(v);
        }
      }
    }
  }
}

// ---------------------------------------------------------------------------
// LayerNorm over D=512 (bf16 in -> bf16 out), one row per block.
// ---------------------------------------------------------------------------
__global__ __launch_bounds__(256) void ln_kernel(
    const bf16u* __restrict__ X, const float* __restrict__ g,
    const float* __restrict__ bta, bf16u* __restrict__ Y)
{
  int row = blockIdx.x, tid = threadIdx.x;
  unsigned int pr = *(const unsigned int*)&X[(size_t)row * DMODEL + 2 * tid];
  float x0 = b2f((bf16u)(pr & 0xffff)), x1 = b2f((bf16u)(pr >> 16));
  __shared__ float red[8];
  int wv = tid >> 6, ln = tid & 63;
  float s = x0 + x1;
  for (int off = 32; off; off >>= 1) s += __shfl_xor(s, off);
  if (ln == 0) red[wv] = s;
  __syncthreads();
  float mu = (red[0] + red[1] + red[2] + red[3]) * (1.0f / DMODEL);
  float d0 = x0 - mu, d1 = x1 - mu;
  float vs = d0 * d0 + d1 * d1;
  for (int off = 32; off; off >>= 1) vs += __shfl_xor(vs, off);
  if (ln == 0) red[4 + wv] = vs;
  __syncthreads();
  float var = (red[4] + red[5] + red[6] + red[7]) * (1.0f / DMODEL);
  float rstd = rsqrtf(var + 1e-6f);
  float y0 = d0 * rstd * g[2 * tid]     + bta[2 * tid];
  float y1 = d1 * rstd * g[2 * tid + 1] + bta[2 * tid + 1];
  *(unsigned int*)&Y[(size_t)row * DMODEL + 2 * tid] = pack2(y0, y1);
}

// ---------------------------------------------------------------------------
__global__ __launch_bounds__(256) void tok_embed_kernel(
    const int* __restrict__ toks, const float* __restrict__ emb,
    const float* __restrict__ pos, bf16u* __restrict__ xb)
{
  int sp = blockIdx.x, b = blockIdx.y;
  int s = sp + NCOND;
  int tok = toks[b * S_TOK + sp];
  const float* er = emb + (size_t)tok * DMODEL;
  const float* pr = pos + (size_t)s * DMODEL;
  size_t ro = ((size_t)b * SEQ + s) * DMODEL;
  int d = threadIdx.x * 2;
  float v0 = er[d]     * 22.62741699796952f + pr[d];
  float v1 = er[d + 1] * 22.62741699796952f + pr[d + 1];
  *(unsigned int*)&xb[ro + d] = pack2(v0, v1);
}

// ---------------------------------------------------------------------------
__global__ __launch_bounds__(256) void cond_embed_kernel(
    const float* __restrict__ conds, const float* __restrict__ W1,
    const float* __restrict__ b1, const float* __restrict__ W2w,
    const float* __restrict__ b2, const float* __restrict__ nullc,
    const float* __restrict__ pos, bf16u* __restrict__ xb)
{
  int ci = blockIdx.x, b = blockIdx.y, tid = threadIdx.x;
  float c = conds[b * NCOND + ci];
  bool cn = isnan(c);
  float cm = cn ? 0.f : c;
  __shared__ float h1[DMODEL / 2];
  h1[tid] = fmaxf(cm * W1[ci * (DMODEL/2) + tid] + b1[ci * (DMODEL/2) + tid], 0.f);
  __syncthreads();
  for (int d = tid; d < DMODEL; d += 256) {
    float acc = b2[ci * DMODEL + d];
    for (int i = 0; i < DMODEL / 2; i++)
      acc = fmaf(h1[i], W2w[((size_t)ci * (DMODEL/2) + i) * DMODEL + d], acc);
    float ce = cn ? nullc[ci * DMODEL + d] : acc;
    xb[((size_t)b * SEQ + ci) * DMODEL + d] = f2b(ce + pos[(size_t)ci * DMODEL + d]);
  }
}

// ---------------------------------------------------------------------------
// E (fp32, all 6 layers) -> bf16.
// ---------------------------------------------------------------------------
__global__ __launch_bounds__(256) void e_conv_kernel(
    const float* __restrict__ E, bf16u* __restrict__ Eb)
{
  int i = (blockIdx.x * 256 + threadIdx.x) * 4;
  float4 v = *(const float4*)&E[i];
  ushort4 o;
  o.x = f2b(v.x); o.y = f2b(v.y); o.z = f2b(v.z); o.w = f2b(v.w);
  *(ushort4*)&Eb[i] = o;
}

// ---------------------------------------------------------------------------
// Split-K MFMA flash attention v5.
// Changes vs v4 (latency-bound per counters: MfmaUtil 6.4%, Occ 13%):
//  - K/V double-buffered in LDS, register-staged (T14): at loop top write the
//    pre-loaded regs for js+1 into buf[cur^1] (concurrent with compute on
//    buf[cur]), issue loads for js+2, compute, ONE barrier per step (was 2).
//    VMEM latency covered by ~2 steps of compute.
//  - E frags read DIRECTLY from global (L2-resident 256KB, shared across all
//    blocks of this layer) — Ebs ring + its staging deleted.
//  - padv from direct toks loads (L1/L2-hot) — padv LDS buffer deleted.
//  - Math (QE single-shuffle, DPP reduce, mask, Ps, slot/LPT) unchanged.
// LDS = 2*9K (K) + 2*9K (V) + 9K (Ps) = 46KB -> 3 blocks/CU.
// ---------------------------------------------------------------------------
__global__ __launch_bounds__(256) void attn_part(
    const bf16u* __restrict__ Q, const bf16u* __restrict__ K,
    const bf16u* __restrict__ Vt_g, const bf16u* __restrict__ Eb16,
    const int* __restrict__ toks, bf16u* __restrict__ pacc,
    float* __restrict__ pstat)
{
  const int bid = blockIdx.x;
  const int g  = bid >> 7;              // (b,h)
  const int it = 31 - ((bid >> 2) & 31);// q-tile, heavy-first (LPT)
  const int c  = bid & 3;               // key chunk
  if (8 * c > it) return;
  const int slot = (g << 7) | (it << 2) | c;   // logical index for partials
  const int b = g >> 3, h = g & 7;
  const int i0 = it * 64;

  __shared__ bf16u Kb[2][64][72];
  __shared__ bf16u Vt[2][64][72];
  __shared__ bf16u Ps[64][72];

  const int tid  = threadIdx.x;
  const int lane = tid & 63;
  const int wave = tid >> 6;
  const int quad = lane >> 4;
  const int l16  = lane & 15;

  const bf16u* qr = Q + ((size_t)(b * SEQ + i0 + wave * 16 + l16)) * DMODEL + h * DHEAD;
  s8frag q0 = *(const s8frag*)&qr[quad * 8];
  s8frag q1 = *(const s8frag*)&qr[32 + quad * 8];

  float m_run[4], l_run[4];
  f4frag acc[4];
#pragma unroll
  for (int r = 0; r < 4; r++) { m_run[r] = -1e30f; l_run[r] = 0.f; }
#pragma unroll
  for (int dt = 0; dt < 4; dt++) acc[dt] = (f4frag){0.f, 0.f, 0.f, 0.f};

  const int js0 = 8 * c;
  const int jsE = min(8 * c + 8, it + 1);
  const int nst = jsE - js0;
  const size_t vtbase = (size_t)(g * DHEAD) * SEQ;

  // register staging: per e, rows (e*256+tid)>>3, 16B chunk ((e*256+tid)&7)*8
  uint4 kreg[2], vreg[2];
  const int s_rr0 = tid >> 3,        s_off0 = (tid & 7) * 8;
  const int s_rr1 = (256 + tid) >> 3, s_off1 = (tid & 7) * 8;

#define STAGE_LOAD(JS) do {                                                     \
    int j0p = (JS) * 64;                                                        \
    kreg[0] = *(const uint4*)&K[((size_t)(b * SEQ + j0p + s_rr0)) * DMODEL + h * DHEAD + s_off0]; \
    kreg[1] = *(const uint4*)&K[((size_t)(b * SEQ + j0p + s_rr1)) * DMODEL + h * DHEAD + s_off1]; \
    vreg[0] = *(const uint4*)&Vt_g[vtbase + (size_t)s_rr0 * SEQ + j0p + s_off0]; \
    vreg[1] = *(const uint4*)&Vt_g[vtbase + (size_t)s_rr1 * SEQ + j0p + s_off1]; \
  } while (0)

#define STAGE_WRITE(BUF) do {                                                   \
    *(uint4*)&Kb[BUF][s_rr0][s_off0] = kreg[0];                                 \
    *(uint4*)&Kb[BUF][s_rr1][s_off1] = kreg[1];                                 \
    *(uint4*)&Vt[BUF][s_rr0][s_off0] = vreg[0];                                 \
    *(uint4*)&Vt[BUF][s_rr1][s_off1] = vreg[1];                                 \
  } while (0)

  STAGE_LOAD(js0);
  STAGE_WRITE(0);
  if (nst > 1) STAGE_LOAD(js0 + 1);
  __syncthreads();

  for (int idx = 0; idx < nst; idx++) {
    const int js = js0 + idx;
    const int cur = idx & 1;
    const int j0 = js * 64;
    const int m0 = 1984 - i0 + j0;   // E row of band col 0

    // write next tile (regs loaded >=1 iter ago) into the other buffer;
    // concurrent with this step's compute on buf[cur]. Then issue js+2 loads.
    if (idx + 1 < nst) STAGE_WRITE(cur ^ 1);
    if (idx + 2 < nst) STAGE_LOAD(js + 2);

    // pad mask direct from toks (L1/L2-hot; consumed after QK/QE)
    float pvv[4];
#pragma unroll
    for (int nt = 0; nt < 4; nt++) {
      int j = j0 + nt * 16 + l16;
      float pv = 0.f;
      if (j >= NCOND && toks[b * S_TOK + j - NCOND] == 0) pv = -1e30f;
      pvv[nt] = pv;
    }

    // QK^T (reads Kb[cur])
    f4frag sc[4];
#pragma unroll
    for (int nt = 0; nt < 4; nt++) {
      s8frag k0 = *(const s8frag*)&Kb[cur][nt * 16 + l16][quad * 8];
      s8frag k1 = *(const s8frag*)&Kb[cur][nt * 16 + l16][32 + quad * 8];
      f4frag cc = (f4frag){0.f, 0.f, 0.f, 0.f};
      cc = __builtin_amdgcn_mfma_f32_16x16x32_bf16(q0, k0, cc, 0, 0, 0);
      cc = __builtin_amdgcn_mfma_f32_16x16x32_bf16(q1, k1, cc, 0, 0, 0);
      sc[nt] = cc;
    }

    // QE: 5 frags covering band cols [(3-wave)*16, (8-wave)*16); E from global
    f4frag qef[5];
#pragma unroll
    for (int f = 0; f < 5; f++) {
      int ct = f + 3 - wave;
      int m = m0 + ct * 16 + l16;
      int row = m > SEQ - 1 ? SEQ - 1 : m;
      const bf16u* erow = Eb16 + (size_t)row * DHEAD;
      s8frag e0 = *(const s8frag*)&erow[quad * 8];
      s8frag e1 = *(const s8frag*)&erow[32 + quad * 8];
      f4frag cc = (f4frag){0.f, 0.f, 0.f, 0.f};
      cc = __builtin_amdgcn_mfma_f32_16x16x32_bf16(q0, e0, cc, 0, 0, 0);
      cc = __builtin_amdgcn_mfma_f32_16x16x32_bf16(q1, e1, cc, 0, 0, 0);
      qef[f] = cc;
    }

    // scores + online softmax; QE gathered by ONE shuffle (select at source).
    float s[4][4], mx[4];
#pragma unroll
    for (int r = 0; r < 4; r++) {
      int rloc = wave * 16 + quad * 4 + r;
      int ig = i0 + rloc;
      int t = quad * 4 + r;
      int v = 63 - 16 * wave + l16 - t;
      int srcl = (lane & 48) | (v & 15);
      bool hiSrc = (l16 < 15 - t);     // target hi <=> this at source lane
#pragma unroll
      for (int nt = 0; nt < 4; nt++) {
        float pre = hiSrc ? qef[nt + 1][r] : qef[nt][r];
        float qe = __shfl(pre, srcl);
        int jl = nt * 16 + l16;
        float sv = (sc[nt][r] + qe) * 0.125f + pvv[nt];
        if (j0 + jl > ig) sv = -1e30f;
        s[nt][r] = sv;
      }
      float m = fmaxf(fmaxf(s[0][r], s[1][r]), fmaxf(s[2][r], s[3][r]));
      float tr;
      DPP_ROR(tr, m, 1); m = fmaxf(m, tr);
      DPP_ROR(tr, m, 2); m = fmaxf(m, tr);
      DPP_ROR(tr, m, 4); m = fmaxf(m, tr);
      DPP_ROR(tr, m, 8); m = fmaxf(m, tr);
      mx[r] = m;
    }
    float alpha[4];
#pragma unroll
    for (int r = 0; r < 4; r++) {
      float m_new = fmaxf(m_run[r], mx[r]);
      alpha[r] = __expf(m_run[r] - m_new);
      float psum = 0.f;
      int rloc = wave * 16 + quad * 4 + r;
#pragma unroll
      for (int nt = 0; nt < 4; nt++) {
        float p = __expf(s[nt][r] - m_new);
        Ps[rloc][nt * 16 + l16] = f2b(p);
        psum += p;
      }
      float tr;
      DPP_ROR(tr, psum, 1); psum += tr;
      DPP_ROR(tr, psum, 2); psum += tr;
      DPP_ROR(tr, psum, 4); psum += tr;
      DPP_ROR(tr, psum, 8); psum += tr;
      l_run[r] = l_run[r] * alpha[r] + psum;
      m_run[r] = m_new;
    }
#pragma unroll
    for (int dt = 0; dt < 4; dt++)
#pragma unroll
      for (int r = 0; r < 4; r++) acc[dt][r] *= alpha[r];

    // P @ V  (Ps rows are wave-local: write+read same wave, lgkmcnt orders)
    s8frag p0 = *(const s8frag*)&Ps[wave * 16 + l16][quad * 8];
    s8frag p1 = *(const s8frag*)&Ps[wave * 16 + l16][32 + quad * 8];
#pragma unroll
    for (int dt = 0; dt < 4; dt++) {
      s8frag v0 = *(const s8frag*)&Vt[cur][dt * 16 + l16][quad * 8];
      s8frag v1 = *(const s8frag*)&Vt[cur][dt * 16 + l16][32 + quad * 8];
      acc[dt] = __builtin_amdgcn_mfma_f32_16x16x32_bf16(p0, v0, acc[dt], 0, 0, 0);
      acc[dt] = __builtin_amdgcn_mfma_f32_16x16x32_bf16(p1, v1, acc[dt], 0, 0, 0);
    }

    // single barrier per step: my buf[cur] reads are done (so next step's
    // STAGE_WRITE may overwrite it) and buf[cur^1] writes are visible.
    if (idx + 1 < nst) __syncthreads();
  }

#undef STAGE_LOAD
#undef STAGE_WRITE

  // write partials (indexed by logical slot, not blockIdx)
#pragma unroll
  for (int r = 0; r < 4; r++) {
    int rloc = wave * 16 + quad * 4 + r;
    if (l16 == 0) {
      pstat[(size_t)slot * 128 + rloc]      = m_run[r];
      pstat[(size_t)slot * 128 + 64 + rloc] = l_run[r];
    }
#pragma unroll
    for (int dt = 0; dt < 4; dt++)
      pacc[(size_t)slot * 4096 + rloc * 64 + dt * 16 + l16] = f2b(acc[dt][r]);
  }
}

// ---------------------------------------------------------------------------
// Merge <=4 chunk partials per (b,h,q-tile); write O (bf16) into qb.
// ---------------------------------------------------------------------------
__global__ __launch_bounds__(256) void attn_combine(
    const bf16u* __restrict__ pacc, const float* __restrict__ pstat,
    bf16u* __restrict__ O)
{
  int bid = blockIdx.x;             // g*32 + it
  int g = bid >> 5, it = bid & 31;
  int b = g >> 3, h = g & 7;
  int i0 = it * 64;
  int nc = (it >> 3) + 1;
  int tid = threadIdx.x;
  int row = tid >> 2, ql = tid & 3;

  float m_tot = -1e30f;
  float mc[4], lc[4];
#pragma unroll
  for (int c = 0; c < 4; c++) {
    if (c < nc) {
      size_t pb = (size_t)(bid * 4 + c) * 128;
      mc[c] = pstat[pb + row];
      lc[c] = pstat[pb + 64 + row];
      m_tot = fmaxf(m_tot, mc[c]);
    }
  }
  float l_tot = 0.f, w[4];
#pragma unroll
  for (int c = 0; c < 4; c++) {
    if (c < nc) { w[c] = __expf(mc[c] - m_tot); l_tot += w[c] * lc[c]; }
    else w[c] = 0.f;
  }
  float inv = 1.0f / l_tot;

  float out[16];
#pragma unroll
  for (int k = 0; k < 16; k++) out[k] = 0.f;
#pragma unroll
  for (int c = 0; c < 4; c++) {
    if (c >= nc) break;
    const bf16u* pa = pacc + (size_t)(bid * 4 + c) * 4096 + row * 64 + ql * 16;
#pragma unroll
    for (int k = 0; k < 16; k++) out[k] += w[c] * b2f(pa[k]);
  }
  bf16u* ob = O + ((size_t)(b * SEQ + i0 + row)) * DMODEL + h * DHEAD + ql * 16;
#pragma unroll
  for (int k = 0; k < 16; k++) ob[k] = f2b(out[k] * inv);
}

// ---------------------------------------------------------------------------
extern "C" void kernel_launch(void* const* d_in, const int* in_sizes, int n_in,
                              void* d_out, int out_size, void* d_ws, size_t ws_size,
                              hipStream_t stream) {
  const int*   toks  = (const int*)  d_in[0];
  const float* conds = (const float*)d_in[1];
  const float* ttc   = (const float*)d_in[2];
  const float* emb   = (const float*)d_in[3];
  const float* pos   = (const float*)d_in[4];
  const float* cW1   = (const float*)d_in[5];
  const float* cb1   = (const float*)d_in[6];
  const float* cW2   = (const float*)d_in[7];
  const float* cb2   = (const float*)d_in[8];
  const float* nullc = (const float*)d_in[9];
  const float* ttcW  = (const float*)d_in[10];
  const float* ttcb  = (const float*)d_in[11];
  const float* Wq    = (const float*)d_in[12];
  const float* Wk    = (const float*)d_in[13];
  const float* Wv    = (const float*)d_in[14];
  const float* Wo    = (const float*)d_in[15];
  const float* bq    = (const float*)d_in[16];
  const float* bk    = (const float*)d_in[17];
  const float* bv    = (const float*)d_in[18];
  const float* bo    = (const float*)d_in[19];
  const float* E     = (const float*)d_in[20];
  const float* fW1   = (const float*)d_in[21];
  const float* fb1   = (const float*)d_in[22];
  const float* fW2   = (const float*)d_in[23];
  const float* fb2   = (const float*)d_in[24];
  const float* ln1g  = (const float*)d_in[25];
  const float* ln1b  = (const float*)d_in[26];
  const float* ln2g  = (const float*)d_in[27];
  const float* ln2b  = (const float*)d_in[28];
  const float* fcW   = (const float*)d_in[29];
  const float* fcb   = (const float*)d_in[30];

  const size_t MB1 = 1024 * 1024;
  const size_t MD = (size_t)MROWS * DMODEL;
  char* p = (char*)d_ws;
  bf16u* xb    = (bf16u*)p; p += 4 * MB1;
  bf16u* qkvb  = (bf16u*)p; p += 12 * MB1;   // qb | kb | vb
  bf16u* hidb  = (bf16u*)p; p += 16 * MB1;   // FFN hidden / pacc alias
  float* pstat = (float*)p; p += 1 * MB1;
  bf16u* vbt   = (bf16u*)p; p += 4 * MB1;    // V transposed
  bf16u* ebf   = (bf16u*)p; p += 1536 * 1024;   // E bf16, 6 layers
  bf16u* WqkvT = (bf16u*)p; p += 9 * MB1;
  bf16u* WoT   = (bf16u*)p; p += 3 * MB1;
  bf16u* W1T   = (bf16u*)p; p += 12 * MB1;
  bf16u* W2T   = (bf16u*)p; p += 12 * MB1;
  bf16u* fcT   = (bf16u*)p; p += 512 * 1024;    // total 75 MB
  bf16u* qb = qkvb;
  bf16u* kb = qkvb + MD;        // out1b aliases kb (disjoint lifetimes)
  bf16u* vb = qkvb + 2 * MD;    // t1b aliases vb (disjoint lifetimes)
  bf16u* out1b = kb;
  bf16u* t1b   = vb;
  bf16u* pacc  = hidb;

  // ---- setup: embeds + all-layer weight transposes + E conversion ----
  cond_embed_kernel<<<dim3(NCOND, BATCH), 256, 0, stream>>>(
      conds, cW1, cb1, cW2, cb2, nullc, pos, xb);
  tok_embed_kernel<<<dim3(S_TOK, BATCH), 256, 0, stream>>>(toks, emb, pos, xb);
  wt_all_kernel<<<6 * 768 + 64, 256, 0, stream>>>(Wq, Wk, Wv, Wo, fW1, fW2, fcW,
      WqkvT, WoT, W1T, W2T, fcT);
  e_conv_kernel<<<(NLAYER * SEQ * DHEAD) / 1024, 256, 0, stream>>>(E, ebf);

  dim3 gQKV(MROWS / 128, 1536 / 128);      // (32,12)
  dim3 gFF1(MROWS / 128, DINNER / 128);    // (32,16)
  dim3 gN512(MROWS / 64, DMODEL / 128);    // (64,4): 256 blocks, RB=2

  for (int l = 0; l < NLAYER; l++) {
    // fused QKV
    mgemm<4><<<gQKV, 256, 0, stream>>>(xb, WqkvT + (size_t)l * 786432,
        bq + l * DMODEL, bk + l * DMODEL, bv + l * DMODEL, nullptr,
        nullptr, qkvb, MROWS, 1536, DMODEL, 4, nullptr, nullptr, nullptr);

    vt_kernel<<<512, 256, 0, stream>>>(vb, vbt);
    attn_part<<<2048, 256, 0, stream>>>(qb, kb, vbt,
        ebf + (size_t)l * SEQ * DHEAD, toks, pacc, pstat);
    attn_combine<<<512, 256, 0, stream>>>(pacc, pstat, qb);

    // t1 = attn @ Wo + bo + x
    mgemm<2><<<gN512, 256, 0, stream>>>(qb, WoT + (size_t)l * 262144,
        bo + l * DMODEL, nullptr, nullptr, xb,
        nullptr, t1b, MROWS, DMODEL, DMODEL, 1, nullptr, nullptr, nullptr);
    ln_kernel<<<MROWS, 256, 0, stream>>>(t1b, ln1g + l * DMODEL, ln1b + l * DMODEL,
        out1b);

    // hid = relu(out1 @ W1 + b1) + chord
    mgemm<4><<<gFF1, 256, 0, stream>>>(out1b, W1T + (size_t)l * 1048576,
        fb1 + l * DINNER, nullptr, nullptr, nullptr,
        nullptr, hidb, MROWS, DINNER, DMODEL, 2, ttc, ttcW, ttcb);
    // t1 = hid @ W2 + b2 + out1
    mgemm<2><<<gN512, 256, 0, stream>>>(hidb, W2T + (size_t)l * 1048576,
        fb2 + l * DMODEL, nullptr, nullptr, out1b,
        nullptr, t1b, MROWS, DMODEL, DINNER, 1, nullptr, nullptr, nullptr);
    ln_kernel<<<MROWS, 256, 0, stream>>>(t1b, ln2g + l * DMODEL, ln2b + l * DMODEL,
        xb);
  }

  // logits = x @ fc_W + fc_b (fp32 out)
  mgemm<2><<<gN512, 256, 0, stream>>>(xb, fcT,
      fcb, nullptr, nullptr, nullptr,
      (float*)d_out, nullptr, MROWS, VOCAB, DMODEL, 3, nullptr, nullptr, nullptr);
}

// Round 4
// 1834.001 us; speedup vs baseline: 1.0680x; 1.0680x over previous
//
#include <hip/hip_runtime.h>
#include <hip/hip_bf16.h>
#include <math.h>

// ---- problem constants ----
#define BATCH  2
#define S_TOK  2046
#define NCOND  2
#define SEQ    2048
#define DMODEL 512
#define DINNER 2048
#define NHEAD  8
#define DHEAD  64
#define NLAYER 6
#define VOCAB  512
#define MROWS  (BATCH*SEQ)   // 4096 rows

typedef unsigned short bf16u;
typedef __attribute__((ext_vector_type(8))) short s8frag;   // 8 bf16 (4 VGPRs)
typedef __attribute__((ext_vector_type(4))) float f4frag;   // 4 fp32 acc

__device__ __forceinline__ float b2f(bf16u u) {
  union { unsigned int i; float f; } v; v.i = ((unsigned int)u) << 16; return v.f;
}
__device__ __forceinline__ bf16u f2b(float f) {
  union { float f; unsigned int i; } v; v.f = f;
  unsigned int x = v.i;
  return (bf16u)((x + 0x7fffu + ((x >> 16) & 1u)) >> 16);
}
__device__ __forceinline__ unsigned int pack2(float a, float b) {
  return (unsigned int)f2b(a) | ((unsigned int)f2b(b) << 16);
}

// DPP row-rotate (within 16-lane row) — VALU-pipe lane exchange, not LDS.
#define DPP_ROR(dst, src, N)                                              \
  dst = __int_as_float(__builtin_amdgcn_update_dpp(                       \
      0, __float_as_int(src), 0x120 + (N), 0xF, 0xF, true))

// ---------------------------------------------------------------------------
// All-layer weight transpose + bf16: dst[N][K] = src[K][N]. One launch.
// ---------------------------------------------------------------------------
__global__ __launch_bounds__(256) void wt_all_kernel(
    const float* __restrict__ Wq, const float* __restrict__ Wk,
    const float* __restrict__ Wv, const float* __restrict__ Wo,
    const float* __restrict__ W1, const float* __restrict__ W2,
    const float* __restrict__ fcW,
    bf16u* __restrict__ qkvT, bf16u* __restrict__ oT,
    bf16u* __restrict__ w1T, bf16u* __restrict__ w2T, bf16u* __restrict__ fcT)
{
  int bid = blockIdx.x;
  const float* src; bf16u* dst; int N, K, kt, nt;
  if (bid < 6 * 768) {
    int L = bid / 768, t = bid - L * 768;
    if (t < 256) {
      int mat = t >> 6, tt = t & 63;
      const float* s4[4] = {Wq, Wk, Wv, Wo};
      src = s4[mat] + (size_t)L * DMODEL * DMODEL;
      dst = (mat < 3) ? (qkvT + (size_t)L * 786432 + (size_t)mat * 262144)
                      : (oT + (size_t)L * 262144);
      K = DMODEL; N = DMODEL; kt = tt >> 3; nt = tt & 7;
    } else if (t < 512) {
      int tt = t - 256;
      src = W1 + (size_t)L * DMODEL * DINNER; dst = w1T + (size_t)L * 1048576;
      K = DMODEL; N = DINNER; kt = tt >> 5; nt = tt & 31;
    } else {
      int tt = t - 512;
      src = W2 + (size_t)L * DINNER * DMODEL; dst = w2T + (size_t)L * 1048576;
      K = DINNER; N = DMODEL; kt = tt >> 3; nt = tt & 7;
    }
  } else {
    int tt = bid - 6 * 768;
    src = fcW; dst = fcT;
    K = DMODEL; N = VOCAB; kt = tt >> 3; nt = tt & 7;
  }
  __shared__ bf16u Ls[64][66];
  int tid = threadIdx.x;
  int c = tid & 63, r4 = tid >> 6;
#pragma unroll
  for (int i = 0; i < 16; i++) {
    int r = i * 4 + r4;
    Ls[r][c] = f2b(src[(size_t)(kt * 64 + r) * N + nt * 64 + c]);
  }
  __syncthreads();
#pragma unroll
  for (int i = 0; i < 16; i++) {
    int rr = i * 4 + r4;
    dst[(size_t)(nt * 64 + rr) * K + kt * 64 + c] = Ls[c][rr];
  }
}

// ---------------------------------------------------------------------------
// V transpose (bf16): vb[(b,i)][h*64+d] -> vbt[(b*8+h)*64+d][i]. 512 blocks.
// ---------------------------------------------------------------------------
__global__ __launch_bounds__(256) void vt_kernel(
    const bf16u* __restrict__ vb, bf16u* __restrict__ vbt)
{
  int bid = blockIdx.x;
  int b = bid >> 8, t = bid & 255;
  int it = t >> 3, h = t & 7;
  __shared__ bf16u Ls[64][66];
  int tid = threadIdx.x;
  int c = tid & 63, r4 = tid >> 6;
#pragma unroll
  for (int i = 0; i < 16; i++) {
    int r = i * 4 + r4;
    Ls[r][c] = vb[(size_t)(b * SEQ + it * 64 + r) * DMODEL + h * DHEAD + c];
  }
  __syncthreads();
#pragma unroll
  for (int i = 0; i < 16; i++) {
    int rr = i * 4 + r4;
    vbt[(size_t)((b * 8 + h) * DHEAD + rr) * SEQ + it * 64 + c] = Ls[c][rr];
  }
}

// ---------------------------------------------------------------------------
// MFMA GEMM, RB m-tiles/wave (4 -> 128x128, 2 -> 64x128).
// modes: 0 +bias->bf16 ; 1 +bias+Rb(bf16)->bf16 ; 2 relu(+bias)+chord->bf16 ;
//        3 +bias->fp32 ; 4 fused-QKV routing -> bf16 (3 slices)
// ---------------------------------------------------------------------------
template <int RB>
__global__ __launch_bounds__(256) void mgemm(
    const bf16u* __restrict__ A, const bf16u* __restrict__ Wt,
    const float* __restrict__ b0, const float* __restrict__ b1,
    const float* __restrict__ b2, const bf16u* __restrict__ Rb,
    float* __restrict__ Cf, bf16u* __restrict__ Cb,
    int M, int N, int K, int mode,
    const float* __restrict__ ttc, const float* __restrict__ ttcW,
    const float* __restrict__ ttcb)
{
  __shared__ bf16u Ab[RB * 32][40];
  __shared__ bf16u Bb[128][40];
  const int tid = threadIdx.x;
  const int lane = tid & 63, wave = tid >> 6;
  const int quad = lane >> 4, l16 = lane & 15;
  const int wm = wave >> 1, wn = wave & 1;
  const int row0 = blockIdx.x * (RB * 32), col0 = blockIdx.y * 128;

  f4frag acc[RB][4];
#pragma unroll
  for (int i = 0; i < RB; i++)
#pragma unroll
    for (int j = 0; j < 4; j++) acc[i][j] = (f4frag){0.f, 0.f, 0.f, 0.f};

  for (int k0 = 0; k0 < K; k0 += 32) {
    if (k0) __syncthreads();
    if constexpr (RB >= 2) {
#pragma unroll
      for (int i = 0; i < RB / 2; i++) {
        int c = tid + i * 256;
        int r = c >> 2, koff = (c & 3) * 8;
        *(uint4*)&Ab[r][koff] = *(const uint4*)&A[(size_t)(row0 + r) * K + k0 + koff];
      }
    } else {
      if (tid < 128) {
        int r = tid >> 2, koff = (tid & 3) * 8;
        *(uint4*)&Ab[r][koff] = *(const uint4*)&A[(size_t)(row0 + r) * K + k0 + koff];
      }
    }
#pragma unroll
    for (int i = 0; i < 2; i++) {
      int c = tid + i * 256;
      int r = c >> 2, koff = (c & 3) * 8;
      *(uint4*)&Bb[r][koff] = *(const uint4*)&Wt[(size_t)(col0 + r) * K + k0 + koff];
    }
    __syncthreads();
    s8frag af[RB], bfr[4];
#pragma unroll
    for (int t = 0; t < RB; t++)
      af[t] = *(const s8frag*)&Ab[wm * (RB * 16) + t * 16 + l16][quad * 8];
#pragma unroll
    for (int t = 0; t < 4; t++)
      bfr[t] = *(const s8frag*)&Bb[wn * 64 + t * 16 + l16][quad * 8];
#pragma unroll
    for (int mt = 0; mt < RB; mt++)
#pragma unroll
      for (int nt = 0; nt < 4; nt++)
        acc[mt][nt] = __builtin_amdgcn_mfma_f32_16x16x32_bf16(
            af[mt], bfr[nt], acc[mt][nt], 0, 0, 0);
  }

#pragma unroll
  for (int mt = 0; mt < RB; mt++) {
#pragma unroll
    for (int r = 0; r < 4; r++) {
      int m = row0 + wm * (RB * 16) + mt * 16 + quad * 4 + r;
      float tval = 0.f;
      if (mode == 2) {
        int bb = m >> 11, s = m & (SEQ - 1);
        int sp = (s < NCOND) ? 0 : (s - NCOND);
        tval = 8.0f - ttc[bb * S_TOK + sp];
      }
#pragma unroll
      for (int nt = 0; nt < 4; nt++) {
        int n = col0 + wn * 64 + nt * 16 + l16;
        if (mode == 4) {
          int sel = n >> 9, nn = n & 511;
          float bv = (sel == 0) ? b0[nn] : ((sel == 1) ? b1[nn] : b2[nn]);
          Cb[(size_t)sel * MROWS * DMODEL + (size_t)m * DMODEL + nn]
              = f2b(acc[mt][nt][r] + bv);
        } else {
          float v = acc[mt][nt][r] + b0[n];
          if (mode == 1)      v += b2f(Rb[(size_t)m * N + n]);
          else if (mode == 2) v = fmaxf(v, 0.f) + tval * ttcW[n] + ttcb[n];
          if (mode == 3) Cf[(size_t)m * N + n] = v;
          else           Cb[(size_t)m * N + n] = f2b(v);
        }
      }
    }
  }
}

// ---------------------------------------------------------------------------
// LayerNorm over D=512 (bf16 in -> bf16 out), one row per block.
// ---------------------------------------------------------------------------
__global__ __launch_bounds__(256) void ln_kernel(
    const bf16u* __restrict__ X, const float* __restrict__ g,
    const float* __restrict__ bta, bf16u* __restrict__ Y)
{
  int row = blockIdx.x, tid = threadIdx.x;
  unsigned int pr = *(const unsigned int*)&X[(size_t)row * DMODEL + 2 * tid];
  float x0 = b2f((bf16u)(pr & 0xffff)), x1 = b2f((bf16u)(pr >> 16));
  __shared__ float red[8];
  int wv = tid >> 6, ln = tid & 63;
  float s = x0 + x1;
  for (int off = 32; off; off >>= 1) s += __shfl_xor(s, off);
  if (ln == 0) red[wv] = s;
  __syncthreads();
  float mu = (red[0] + red[1] + red[2] + red[3]) * (1.0f / DMODEL);
  float d0 = x0 - mu, d1 = x1 - mu;
  float vs = d0 * d0 + d1 * d1;
  for (int off = 32; off; off >>= 1) vs += __shfl_xor(vs, off);
  if (ln == 0) red[4 + wv] = vs;
  __syncthreads();
  float var = (red[4] + red[5] + red[6] + red[7]) * (1.0f / DMODEL);
  float rstd = rsqrtf(var + 1e-6f);
  float y0 = d0 * rstd * g[2 * tid]     + bta[2 * tid];
  float y1 = d1 * rstd * g[2 * tid + 1] + bta[2 * tid + 1];
  *(unsigned int*)&Y[(size_t)row * DMODEL + 2 * tid] = pack2(y0, y1);
}

// ---------------------------------------------------------------------------
__global__ __launch_bounds__(256) void tok_embed_kernel(
    const int* __restrict__ toks, const float* __restrict__ emb,
    const float* __restrict__ pos, bf16u* __restrict__ xb)
{
  int sp = blockIdx.x, b = blockIdx.y;
  int s = sp + NCOND;
  int tok = toks[b * S_TOK + sp];
  const float* er = emb + (size_t)tok * DMODEL;
  const float* pr = pos + (size_t)s * DMODEL;
  size_t ro = ((size_t)b * SEQ + s) * DMODEL;
  int d = threadIdx.x * 2;
  float v0 = er[d]     * 22.62741699796952f + pr[d];
  float v1 = er[d + 1] * 22.62741699796952f + pr[d + 1];
  *(unsigned int*)&xb[ro + d] = pack2(v0, v1);
}

// ---------------------------------------------------------------------------
__global__ __launch_bounds__(256) void cond_embed_kernel(
    const float* __restrict__ conds, const float* __restrict__ W1,
    const float* __restrict__ b1, const float* __restrict__ W2w,
    const float* __restrict__ b2, const float* __restrict__ nullc,
    const float* __restrict__ pos, bf16u* __restrict__ xb)
{
  int ci = blockIdx.x, b = blockIdx.y, tid = threadIdx.x;
  float c = conds[b * NCOND + ci];
  bool cn = isnan(c);
  float cm = cn ? 0.f : c;
  __shared__ float h1[DMODEL / 2];
  h1[tid] = fmaxf(cm * W1[ci * (DMODEL/2) + tid] + b1[ci * (DMODEL/2) + tid], 0.f);
  __syncthreads();
  for (int d = tid; d < DMODEL; d += 256) {
    float acc = b2[ci * DMODEL + d];
    for (int i = 0; i < DMODEL / 2; i++)
      acc = fmaf(h1[i], W2w[((size_t)ci * (DMODEL/2) + i) * DMODEL + d], acc);
    float ce = cn ? nullc[ci * DMODEL + d] : acc;
    xb[((size_t)b * SEQ + ci) * DMODEL + d] = f2b(ce + pos[(size_t)ci * DMODEL + d]);
  }
}

// ---------------------------------------------------------------------------
// E (fp32, all 6 layers) -> bf16.
// ---------------------------------------------------------------------------
__global__ __launch_bounds__(256) void e_conv_kernel(
    const float* __restrict__ E, bf16u* __restrict__ Eb)
{
  int i = (blockIdx.x * 256 + threadIdx.x) * 4;
  float4 v = *(const float4*)&E[i];
  ushort4 o;
  o.x = f2b(v.x); o.y = f2b(v.y); o.z = f2b(v.z); o.w = f2b(v.w);
  *(ushort4*)&Eb[i] = o;
}

// ---------------------------------------------------------------------------
// Split-K MFMA flash attention v6.
// v5 post-mortem: E-from-global put 10 scattered VMEM loads in front of the
// QE MFMAs each step (MfmaUtil 6.4->3.7, +2MB HBM from per-XCD E copies).
// v6 = v4's all-LDS compute + register prefetch (T14 issue-early/write-late):
//  - SINGLE-buffered K/V/E in LDS (46KB -> 3 blocks/CU like v4); the regs
//    are the second buffer.
//  - During compute(js): issue global loads for js+1 into kreg/vreg/ereg.
//  - At top of js+1: pure ds_write of those regs (no VMEM wait exposed).
//  - barrier1 after write phase (drains nothing fresh); barrier2 at step end
//    (drains loads issued ~1500cy earlier, mostly hidden).
//  - E ring 128 rows, QE single-shuffle, DPP reductions, toks-direct pad
//    mask, LPT order, slot indexing: all carried over (verified).
// ---------------------------------------------------------------------------
__global__ __launch_bounds__(256) void attn_part(
    const bf16u* __restrict__ Q, const bf16u* __restrict__ K,
    const bf16u* __restrict__ Vt_g, const bf16u* __restrict__ Eb16,
    const int* __restrict__ toks, bf16u* __restrict__ pacc,
    float* __restrict__ pstat)
{
  const int bid = blockIdx.x;
  const int g  = bid >> 7;              // (b,h)
  const int it = 31 - ((bid >> 2) & 31);// q-tile, heavy-first (LPT)
  const int c  = bid & 3;               // key chunk
  if (8 * c > it) return;
  const int slot = (g << 7) | (it << 2) | c;   // logical index for partials
  const int b = g >> 3, h = g & 7;
  const int i0 = it * 64;

  __shared__ bf16u Kb[64][72];
  __shared__ bf16u Vt[64][72];
  __shared__ bf16u Ebs[128][72];
  __shared__ bf16u Ps[64][72];

  const int tid  = threadIdx.x;
  const int lane = tid & 63;
  const int wave = tid >> 6;
  const int quad = lane >> 4;
  const int l16  = lane & 15;

  const bf16u* qr = Q + ((size_t)(b * SEQ + i0 + wave * 16 + l16)) * DMODEL + h * DHEAD;
  s8frag q0 = *(const s8frag*)&qr[quad * 8];
  s8frag q1 = *(const s8frag*)&qr[32 + quad * 8];

  float m_run[4], l_run[4];
  f4frag acc[4];
#pragma unroll
  for (int r = 0; r < 4; r++) { m_run[r] = -1e30f; l_run[r] = 0.f; }
#pragma unroll
  for (int dt = 0; dt < 4; dt++) acc[dt] = (f4frag){0.f, 0.f, 0.f, 0.f};

  const int js0 = 8 * c;
  const int jsE = min(8 * c + 8, it + 1);
  const int nst = jsE - js0;
  const size_t vtbase = (size_t)(g * DHEAD) * SEQ;

  // register staging: thread covers 2x16B chunks of each 64x128B tile.
  uint4 kreg[2], vreg[2], ereg[2];
  const int s_rr0 = tid >> 3;          // rows 0..31
  const int s_rr1 = 32 + (tid >> 3);   // rows 32..63
  const int s_off = (tid & 7) * 8;     // 16B chunk (8 bf16)

#define STAGE_LOAD_KV(JS) do {                                                  \
    int j0p = (JS) * 64;                                                        \
    kreg[0] = *(const uint4*)&K[((size_t)(b * SEQ + j0p + s_rr0)) * DMODEL + h * DHEAD + s_off]; \
    kreg[1] = *(const uint4*)&K[((size_t)(b * SEQ + j0p + s_rr1)) * DMODEL + h * DHEAD + s_off]; \
    vreg[0] = *(const uint4*)&Vt_g[vtbase + (size_t)s_rr0 * SEQ + j0p + s_off]; \
    vreg[1] = *(const uint4*)&Vt_g[vtbase + (size_t)s_rr1 * SEQ + j0p + s_off]; \
  } while (0)

#define STAGE_LOAD_E(JS) do {                                                   \
    int mb = 1984 - i0 + (JS) * 64 + 64;                                        \
    int ma = mb + s_rr0, mbb = mb + s_rr1;                                      \
    int ra = ma > SEQ - 1 ? SEQ - 1 : ma;                                       \
    int rb = mbb > SEQ - 1 ? SEQ - 1 : mbb;                                     \
    ereg[0] = *(const uint4*)&Eb16[(size_t)ra * DHEAD + s_off];                 \
    ereg[1] = *(const uint4*)&Eb16[(size_t)rb * DHEAD + s_off];                 \
  } while (0)

#define STAGE_WRITE_KV() do {                                                   \
    *(uint4*)&Kb[s_rr0][s_off] = kreg[0];                                       \
    *(uint4*)&Kb[s_rr1][s_off] = kreg[1];                                       \
    *(uint4*)&Vt[s_rr0][s_off] = vreg[0];                                       \
    *(uint4*)&Vt[s_rr1][s_off] = vreg[1];                                       \
  } while (0)

#define STAGE_WRITE_E(JS) do {                                                  \
    int mb = 1984 - i0 + (JS) * 64 + 64;                                        \
    *(uint4*)&Ebs[(mb + s_rr0) & 127][s_off] = ereg[0];                         \
    *(uint4*)&Ebs[(mb + s_rr1) & 127][s_off] = ereg[1];                         \
  } while (0)

  // prologue: K/V for js0 into regs; E ring 128 rows direct copy.
  STAGE_LOAD_KV(js0);
  {
    int mb = 1984 - i0 + js0 * 64;
#pragma unroll
    for (int e = 0; e < 4; e++) {
      int cc = e * 256 + tid;
      int er = cc >> 3, doff = (cc & 7) * 8;
      int m = mb + er; int row = m > SEQ - 1 ? SEQ - 1 : m;
      *(uint4*)&Ebs[m & 127][doff] = *(const uint4*)&Eb16[(size_t)row * DHEAD + doff];
    }
  }

  for (int idx = 0; idx < nst; idx++) {
    const int js = js0 + idx;
    const int j0 = js * 64;
    const int m0 = 1984 - i0 + j0;   // E row of band col 0

    // ---- write phase: regs -> LDS (no VMEM latency exposed) ----
    STAGE_WRITE_KV();
    if (idx > 0) STAGE_WRITE_E(js);   // idx==0: prologue filled all 128 rows
    __syncthreads();                  // b1: cheap (no fresh VMEM in flight)

    // ---- compute phase ----
    // QK^T (reads Kb)
    f4frag sc[4];
#pragma unroll
    for (int nt = 0; nt < 4; nt++) {
      s8frag k0 = *(const s8frag*)&Kb[nt * 16 + l16][quad * 8];
      s8frag k1 = *(const s8frag*)&Kb[nt * 16 + l16][32 + quad * 8];
      f4frag cc = (f4frag){0.f, 0.f, 0.f, 0.f};
      cc = __builtin_amdgcn_mfma_f32_16x16x32_bf16(q0, k0, cc, 0, 0, 0);
      cc = __builtin_amdgcn_mfma_f32_16x16x32_bf16(q1, k1, cc, 0, 0, 0);
      sc[nt] = cc;
    }

    // QE: 5 frags covering band cols [(3-wave)*16, (8-wave)*16)  (reads Ebs)
    f4frag qef[5];
#pragma unroll
    for (int f = 0; f < 5; f++) {
      int ct = f + 3 - wave;
      int m = m0 + ct * 16 + l16;
      const bf16u* erow = &Ebs[m & 127][0];
      s8frag e0 = *(const s8frag*)&erow[quad * 8];
      s8frag e1 = *(const s8frag*)&erow[32 + quad * 8];
      f4frag cc = (f4frag){0.f, 0.f, 0.f, 0.f};
      cc = __builtin_amdgcn_mfma_f32_16x16x32_bf16(q0, e0, cc, 0, 0, 0);
      cc = __builtin_amdgcn_mfma_f32_16x16x32_bf16(q1, e1, cc, 0, 0, 0);
      qef[f] = cc;
    }

    // prefetch next step into regs; latency hides under softmax+PV (~1500cy)
    if (idx + 1 < nst) { STAGE_LOAD_KV(js + 1); STAGE_LOAD_E(js + 1); }

    // pad mask direct from toks (L1/L2-hot)
    float pvv[4];
#pragma unroll
    for (int nt = 0; nt < 4; nt++) {
      int j = j0 + nt * 16 + l16;
      float pv = 0.f;
      if (j >= NCOND && toks[b * S_TOK + j - NCOND] == 0) pv = -1e30f;
      pvv[nt] = pv;
    }

    // scores + online softmax; QE gathered by ONE shuffle (select at source).
    float s[4][4], mx[4];
#pragma unroll
    for (int r = 0; r < 4; r++) {
      int rloc = wave * 16 + quad * 4 + r;
      int ig = i0 + rloc;
      int t = quad * 4 + r;
      int v = 63 - 16 * wave + l16 - t;
      int srcl = (lane & 48) | (v & 15);
      bool hiSrc = (l16 < 15 - t);     // target hi <=> this at source lane
#pragma unroll
      for (int nt = 0; nt < 4; nt++) {
        float pre = hiSrc ? qef[nt + 1][r] : qef[nt][r];
        float qe = __shfl(pre, srcl);
        int jl = nt * 16 + l16;
        float sv = (sc[nt][r] + qe) * 0.125f + pvv[nt];
        if (j0 + jl > ig) sv = -1e30f;
        s[nt][r] = sv;
      }
      float m = fmaxf(fmaxf(s[0][r], s[1][r]), fmaxf(s[2][r], s[3][r]));
      float tr;
      DPP_ROR(tr, m, 1); m = fmaxf(m, tr);
      DPP_ROR(tr, m, 2); m = fmaxf(m, tr);
      DPP_ROR(tr, m, 4); m = fmaxf(m, tr);
      DPP_ROR(tr, m, 8); m = fmaxf(m, tr);
      mx[r] = m;
    }
    float alpha[4];
#pragma unroll
    for (int r = 0; r < 4; r++) {
      float m_new = fmaxf(m_run[r], mx[r]);
      alpha[r] = __expf(m_run[r] - m_new);
      float psum = 0.f;
      int rloc = wave * 16 + quad * 4 + r;
#pragma unroll
      for (int nt = 0; nt < 4; nt++) {
        float p = __expf(s[nt][r] - m_new);
        Ps[rloc][nt * 16 + l16] = f2b(p);
        psum += p;
      }
      float tr;
      DPP_ROR(tr, psum, 1); psum += tr;
      DPP_ROR(tr, psum, 2); psum += tr;
      DPP_ROR(tr, psum, 4); psum += tr;
      DPP_ROR(tr, psum, 8); psum += tr;
      l_run[r] = l_run[r] * alpha[r] + psum;
      m_run[r] = m_new;
    }
#pragma unroll
    for (int dt = 0; dt < 4; dt++)
#pragma unroll
      for (int r = 0; r < 4; r++) acc[dt][r] *= alpha[r];

    // P @ V  (Ps rows wave-local; lgkmcnt orders write->read)
    s8frag p0 = *(const s8frag*)&Ps[wave * 16 + l16][quad * 8];
    s8frag p1 = *(const s8frag*)&Ps[wave * 16 + l16][32 + quad * 8];
#pragma unroll
    for (int dt = 0; dt < 4; dt++) {
      s8frag v0 = *(const s8frag*)&Vt[dt * 16 + l16][quad * 8];
      s8frag v1 = *(const s8frag*)&Vt[dt * 16 + l16][32 + quad * 8];
      acc[dt] = __builtin_amdgcn_mfma_f32_16x16x32_bf16(p0, v0, acc[dt], 0, 0, 0);
      acc[dt] = __builtin_amdgcn_mfma_f32_16x16x32_bf16(p1, v1, acc[dt], 0, 0, 0);
    }

    // b2: all waves done reading Kb/Vt/Ebs-window for this step; next step's
    // write phase may overwrite. Drains the js+1 prefetch (issued ~1500cy ago).
    if (idx + 1 < nst) __syncthreads();
  }

#undef STAGE_LOAD_KV
#undef STAGE_LOAD_E
#undef STAGE_WRITE_KV
#undef STAGE_WRITE_E

  // write partials (indexed by logical slot, not blockIdx)
#pragma unroll
  for (int r = 0; r < 4; r++) {
    int rloc = wave * 16 + quad * 4 + r;
    if (l16 == 0) {
      pstat[(size_t)slot * 128 + rloc]      = m_run[r];
      pstat[(size_t)slot * 128 + 64 + rloc] = l_run[r];
    }
#pragma unroll
    for (int dt = 0; dt < 4; dt++)
      pacc[(size_t)slot * 4096 + rloc * 64 + dt * 16 + l16] = f2b(acc[dt][r]);
  }
}

// ---------------------------------------------------------------------------
// Merge <=4 chunk partials per (b,h,q-tile); write O (bf16) into qb.
// ---------------------------------------------------------------------------
__global__ __launch_bounds__(256) void attn_combine(
    const bf16u* __restrict__ pacc, const float* __restrict__ pstat,
    bf16u* __restrict__ O)
{
  int bid = blockIdx.x;             // g*32 + it
  int g = bid >> 5, it = bid & 31;
  int b = g >> 3, h = g & 7;
  int i0 = it * 64;
  int nc = (it >> 3) + 1;
  int tid = threadIdx.x;
  int row = tid >> 2, ql = tid & 3;

  float m_tot = -1e30f;
  float mc[4], lc[4];
#pragma unroll
  for (int c = 0; c < 4; c++) {
    if (c < nc) {
      size_t pb = (size_t)(bid * 4 + c) * 128;
      mc[c] = pstat[pb + row];
      lc[c] = pstat[pb + 64 + row];
      m_tot = fmaxf(m_tot, mc[c]);
    }
  }
  float l_tot = 0.f, w[4];
#pragma unroll
  for (int c = 0; c < 4; c++) {
    if (c < nc) { w[c] = __expf(mc[c] - m_tot); l_tot += w[c] * lc[c]; }
    else w[c] = 0.f;
  }
  float inv = 1.0f / l_tot;

  float out[16];
#pragma unroll
  for (int k = 0; k < 16; k++) out[k] = 0.f;
#pragma unroll
  for (int c = 0; c < 4; c++) {
    if (c >= nc) break;
    const bf16u* pa = pacc + (size_t)(bid * 4 + c) * 4096 + row * 64 + ql * 16;
#pragma unroll
    for (int k = 0; k < 16; k++) out[k] += w[c] * b2f(pa[k]);
  }
  bf16u* ob = O + ((size_t)(b * SEQ + i0 + row)) * DMODEL + h * DHEAD + ql * 16;
#pragma unroll
  for (int k = 0; k < 16; k++) ob[k] = f2b(out[k] * inv);
}

// ---------------------------------------------------------------------------
extern "C" void kernel_launch(void* const* d_in, const int* in_sizes, int n_in,
                              void* d_out, int out_size, void* d_ws, size_t ws_size,
                              hipStream_t stream) {
  const int*   toks  = (const int*)  d_in[0];
  const float* conds = (const float*)d_in[1];
  const float* ttc   = (const float*)d_in[2];
  const float* emb   = (const float*)d_in[3];
  const float* pos   = (const float*)d_in[4];
  const float* cW1   = (const float*)d_in[5];
  const float* cb1   = (const float*)d_in[6];
  const float* cW2   = (const float*)d_in[7];
  const float* cb2   = (const float*)d_in[8];
  const float* nullc = (const float*)d_in[9];
  const float* ttcW  = (const float*)d_in[10];
  const float* ttcb  = (const float*)d_in[11];
  const float* Wq    = (const float*)d_in[12];
  const float* Wk    = (const float*)d_in[13];
  const float* Wv    = (const float*)d_in[14];
  const float* Wo    = (const float*)d_in[15];
  const float* bq    = (const float*)d_in[16];
  const float* bk    = (const float*)d_in[17];
  const float* bv    = (const float*)d_in[18];
  const float* bo    = (const float*)d_in[19];
  const float* E     = (const float*)d_in[20];
  const float* fW1   = (const float*)d_in[21];
  const float* fb1   = (const float*)d_in[22];
  const float* fW2   = (const float*)d_in[23];
  const float* fb2   = (const float*)d_in[24];
  const float* ln1g  = (const float*)d_in[25];
  const float* ln1b  = (const float*)d_in[26];
  const float* ln2g  = (const float*)d_in[27];
  const float* ln2b  = (const float*)d_in[28];
  const float* fcW   = (const float*)d_in[29];
  const float* fcb   = (const float*)d_in[30];

  const size_t MB1 = 1024 * 1024;
  const size_t MD = (size_t)MROWS * DMODEL;
  char* p = (char*)d_ws;
  bf16u* xb    = (bf16u*)p; p += 4 * MB1;
  bf16u* qkvb  = (bf16u*)p; p += 12 * MB1;   // qb | kb | vb
  bf16u* hidb  = (bf16u*)p; p += 16 * MB1;   // FFN hidden / pacc alias
  float* pstat = (float*)p; p += 1 * MB1;
  bf16u* vbt   = (bf16u*)p; p += 4 * MB1;    // V transposed
  bf16u* ebf   = (bf16u*)p; p += 1536 * 1024;   // E bf16, 6 layers
  bf16u* WqkvT = (bf16u*)p; p += 9 * MB1;
  bf16u* WoT   = (bf16u*)p; p += 3 * MB1;
  bf16u* W1T   = (bf16u*)p; p += 12 * MB1;
  bf16u* W2T   = (bf16u*)p; p += 12 * MB1;
  bf16u* fcT   = (bf16u*)p; p += 512 * 1024;    // total 75 MB
  bf16u* qb = qkvb;
  bf16u* kb = qkvb + MD;        // out1b aliases kb (disjoint lifetimes)
  bf16u* vb = qkvb + 2 * MD;    // t1b aliases vb (disjoint lifetimes)
  bf16u* out1b = kb;
  bf16u* t1b   = vb;
  bf16u* pacc  = hidb;

  // ---- setup: embeds + all-layer weight transposes + E conversion ----
  cond_embed_kernel<<<dim3(NCOND, BATCH), 256, 0, stream>>>(
      conds, cW1, cb1, cW2, cb2, nullc, pos, xb);
  tok_embed_kernel<<<dim3(S_TOK, BATCH), 256, 0, stream>>>(toks, emb, pos, xb);
  wt_all_kernel<<<6 * 768 + 64, 256, 0, stream>>>(Wq, Wk, Wv, Wo, fW1, fW2, fcW,
      WqkvT, WoT, W1T, W2T, fcT);
  e_conv_kernel<<<(NLAYER * SEQ * DHEAD) / 1024, 256, 0, stream>>>(E, ebf);

  dim3 gQKV(MROWS / 128, 1536 / 128);      // (32,12)
  dim3 gFF1(MROWS / 128, DINNER / 128);    // (32,16)
  dim3 gN512(MROWS / 64, DMODEL / 128);    // (64,4): 256 blocks, RB=2

  for (int l = 0; l < NLAYER; l++) {
    // fused QKV
    mgemm<4><<<gQKV, 256, 0, stream>>>(xb, WqkvT + (size_t)l * 786432,
        bq + l * DMODEL, bk + l * DMODEL, bv + l * DMODEL, nullptr,
        nullptr, qkvb, MROWS, 1536, DMODEL, 4, nullptr, nullptr, nullptr);

    vt_kernel<<<512, 256, 0, stream>>>(vb, vbt);
    attn_part<<<2048, 256, 0, stream>>>(qb, kb, vbt,
        ebf + (size_t)l * SEQ * DHEAD, toks, pacc, pstat);
    attn_combine<<<512, 256, 0, stream>>>(pacc, pstat, qb);

    // t1 = attn @ Wo + bo + x
    mgemm<2><<<gN512, 256, 0, stream>>>(qb, WoT + (size_t)l * 262144,
        bo + l * DMODEL, nullptr, nullptr, xb,
        nullptr, t1b, MROWS, DMODEL, DMODEL, 1, nullptr, nullptr, nullptr);
    ln_kernel<<<MROWS, 256, 0, stream>>>(t1b, ln1g + l * DMODEL, ln1b + l * DMODEL,
        out1b);

    // hid = relu(out1 @ W1 + b1) + chord
    mgemm<4><<<gFF1, 256, 0, stream>>>(out1b, W1T + (size_t)l * 1048576,
        fb1 + l * DINNER, nullptr, nullptr, nullptr,
        nullptr, hidb, MROWS, DINNER, DMODEL, 2, ttc, ttcW, ttcb);
    // t1 = hid @ W2 + b2 + out1
    mgemm<2><<<gN512, 256, 0, stream>>>(hidb, W2T + (size_t)l * 1048576,
        fb2 + l * DMODEL, nullptr, nullptr, out1b,
        nullptr, t1b, MROWS, DMODEL, DINNER, 1, nullptr, nullptr, nullptr);
    ln_kernel<<<MROWS, 256, 0, stream>>>(t1b, ln2g + l * DMODEL, ln2b + l * DMODEL,
        xb);
  }

  // logits = x @ fc_W + fc_b (fp32 out)
  mgemm<2><<<gN512, 256, 0, stream>>>(xb, fcT,
      fcb, nullptr, nullptr, nullptr,
      (float*)d_out, nullptr, MROWS, VOCAB, DMODEL, 3, nullptr, nullptr, nullptr);
}

// Round 5
// 1555.740 us; speedup vs baseline: 1.2590x; 1.1789x over previous
//
#include <hip/hip_runtime.h>
#include <hip/hip_bf16.h>
#include <math.h>

// ---- problem constants ----
#define BATCH  2
#define S_TOK  2046
#define NCOND  2
#define SEQ    2048
#define DMODEL 512
#define DINNER 2048
#define NHEAD  8
#define DHEAD  64
#define NLAYER 6
#define VOCAB  512
#define MROWS  (BATCH*SEQ)   // 4096 rows

typedef unsigned short bf16u;
typedef __attribute__((ext_vector_type(8))) short s8frag;   // 8 bf16 (4 VGPRs)
typedef __attribute__((ext_vector_type(4))) float f4frag;   // 4 fp32 acc

__device__ __forceinline__ float b2f(bf16u u) {
  union { unsigned int i; float f; } v; v.i = ((unsigned int)u) << 16; return v.f;
}
__device__ __forceinline__ bf16u f2b(float f) {
  union { float f; unsigned int i; } v; v.f = f;
  unsigned int x = v.i;
  return (bf16u)((x + 0x7fffu + ((x >> 16) & 1u)) >> 16);
}
__device__ __forceinline__ unsigned int pack2(float a, float b) {
  return (unsigned int)f2b(a) | ((unsigned int)f2b(b) << 16);
}

// DPP row-rotate (within 16-lane row) — VALU-pipe lane exchange, not LDS.
#define DPP_ROR(dst, src, N)                                              \
  dst = __int_as_float(__builtin_amdgcn_update_dpp(                       \
      0, __float_as_int(src), 0x120 + (N), 0xF, 0xF, true))

// ---------------------------------------------------------------------------
// All-layer weight transpose + bf16: dst[N][K] = src[K][N]. One launch.
// blocks: 6 layers x 768 (q64|k64|v64|o64|W1 256|W2 256) + 64 (fc) = 4672.
// ---------------------------------------------------------------------------
__global__ __launch_bounds__(256) void wt_all_kernel(
    const float* __restrict__ Wq, const float* __restrict__ Wk,
    const float* __restrict__ Wv, const float* __restrict__ Wo,
    const float* __restrict__ W1, const float* __restrict__ W2,
    const float* __restrict__ fcW,
    bf16u* __restrict__ qkvT, bf16u* __restrict__ oT,
    bf16u* __restrict__ w1T, bf16u* __restrict__ w2T, bf16u* __restrict__ fcT)
{
  int bid = blockIdx.x;
  const float* src; bf16u* dst; int N, K, kt, nt;
  if (bid < 6 * 768) {
    int L = bid / 768, t = bid - L * 768;
    if (t < 256) {
      int mat = t >> 6, tt = t & 63;
      const float* s4[4] = {Wq, Wk, Wv, Wo};
      src = s4[mat] + (size_t)L * DMODEL * DMODEL;
      dst = (mat < 3) ? (qkvT + (size_t)L * 786432 + (size_t)mat * 262144)
                      : (oT + (size_t)L * 262144);
      K = DMODEL; N = DMODEL; kt = tt >> 3; nt = tt & 7;
    } else if (t < 512) {
      int tt = t - 256;
      src = W1 + (size_t)L * DMODEL * DINNER; dst = w1T + (size_t)L * 1048576;
      K = DMODEL; N = DINNER; kt = tt >> 5; nt = tt & 31;
    } else {
      int tt = t - 512;
      src = W2 + (size_t)L * DINNER * DMODEL; dst = w2T + (size_t)L * 1048576;
      K = DINNER; N = DMODEL; kt = tt >> 3; nt = tt & 7;
    }
  } else {
    int tt = bid - 6 * 768;
    src = fcW; dst = fcT;
    K = DMODEL; N = VOCAB; kt = tt >> 3; nt = tt & 7;
  }
  __shared__ bf16u Ls[64][66];
  int tid = threadIdx.x;
  int c = tid & 63, r4 = tid >> 6;
#pragma unroll
  for (int i = 0; i < 16; i++) {
    int r = i * 4 + r4;
    Ls[r][c] = f2b(src[(size_t)(kt * 64 + r) * N + nt * 64 + c]);
  }
  __syncthreads();
#pragma unroll
  for (int i = 0; i < 16; i++) {
    int rr = i * 4 + r4;
    dst[(size_t)(nt * 64 + rr) * K + kt * 64 + c] = Ls[c][rr];
  }
}

// ---------------------------------------------------------------------------
// MFMA GEMM, RB m-tiles/wave (4 -> 128x128, 2 -> 64x128, 1 -> 32x128).
// modes: 0 +bias->bf16 ; 1 +bias+Rb(bf16)->bf16 ; 2 relu(+bias)+chord->bf16 ;
//        3 +bias->fp32 ; 4 fused-QKV routing -> bf16 (Q,K slices to Cb;
//        V slice written TRANSPOSED to Cf-as-bf16u in vbt layout
//        [(b*8+h)*64+d][i] — fuses the old vt_kernel).
// ---------------------------------------------------------------------------
template <int RB>
__global__ __launch_bounds__(256) void mgemm(
    const bf16u* __restrict__ A, const bf16u* __restrict__ Wt,
    const float* __restrict__ b0, const float* __restrict__ b1,
    const float* __restrict__ b2, const bf16u* __restrict__ Rb,
    float* __restrict__ Cf, bf16u* __restrict__ Cb,
    int M, int N, int K, int mode,
    const float* __restrict__ ttc, const float* __restrict__ ttcW,
    const float* __restrict__ ttcb)
{
  __shared__ bf16u Ab[RB * 32][40];
  __shared__ bf16u Bb[128][40];
  const int tid = threadIdx.x;
  const int lane = tid & 63, wave = tid >> 6;
  const int quad = lane >> 4, l16 = lane & 15;
  const int wm = wave >> 1, wn = wave & 1;
  const int row0 = blockIdx.x * (RB * 32), col0 = blockIdx.y * 128;

  f4frag acc[RB][4];
#pragma unroll
  for (int i = 0; i < RB; i++)
#pragma unroll
    for (int j = 0; j < 4; j++) acc[i][j] = (f4frag){0.f, 0.f, 0.f, 0.f};

  for (int k0 = 0; k0 < K; k0 += 32) {
    if (k0) __syncthreads();
    if constexpr (RB >= 2) {
#pragma unroll
      for (int i = 0; i < RB / 2; i++) {
        int c = tid + i * 256;
        int r = c >> 2, koff = (c & 3) * 8;
        *(uint4*)&Ab[r][koff] = *(const uint4*)&A[(size_t)(row0 + r) * K + k0 + koff];
      }
    } else {
      if (tid < 128) {
        int r = tid >> 2, koff = (tid & 3) * 8;
        *(uint4*)&Ab[r][koff] = *(const uint4*)&A[(size_t)(row0 + r) * K + k0 + koff];
      }
    }
#pragma unroll
    for (int i = 0; i < 2; i++) {
      int c = tid + i * 256;
      int r = c >> 2, koff = (c & 3) * 8;
      *(uint4*)&Bb[r][koff] = *(const uint4*)&Wt[(size_t)(col0 + r) * K + k0 + koff];
    }
    __syncthreads();
    s8frag af[RB], bfr[4];
#pragma unroll
    for (int t = 0; t < RB; t++)
      af[t] = *(const s8frag*)&Ab[wm * (RB * 16) + t * 16 + l16][quad * 8];
#pragma unroll
    for (int t = 0; t < 4; t++)
      bfr[t] = *(const s8frag*)&Bb[wn * 64 + t * 16 + l16][quad * 8];
#pragma unroll
    for (int mt = 0; mt < RB; mt++)
#pragma unroll
      for (int nt = 0; nt < 4; nt++)
        acc[mt][nt] = __builtin_amdgcn_mfma_f32_16x16x32_bf16(
            af[mt], bfr[nt], acc[mt][nt], 0, 0, 0);
  }

#pragma unroll
  for (int mt = 0; mt < RB; mt++) {
#pragma unroll
    for (int r = 0; r < 4; r++) {
      int m = row0 + wm * (RB * 16) + mt * 16 + quad * 4 + r;
      float tval = 0.f;
      if (mode == 2) {
        int bb = m >> 11, s = m & (SEQ - 1);
        int sp = (s < NCOND) ? 0 : (s - NCOND);
        tval = 8.0f - ttc[bb * S_TOK + sp];
      }
#pragma unroll
      for (int nt = 0; nt < 4; nt++) {
        int n = col0 + wn * 64 + nt * 16 + l16;
        if (mode == 4) {
          int sel = n >> 9, nn = n & 511;
          float bv = (sel == 0) ? b0[nn] : ((sel == 1) ? b1[nn] : b2[nn]);
          float vv = acc[mt][nt][r] + bv;
          if (sel < 2) {
            Cb[(size_t)sel * MROWS * DMODEL + (size_t)m * DMODEL + nn] = f2b(vv);
          } else {
            // V slice -> vbt[(b*8+h)*64+d][i]
            int hh = nn >> 6, dd = nn & 63;
            int bbb = m >> 11, ii = m & (SEQ - 1);
            ((bf16u*)Cf)[((size_t)((bbb * 8 + hh) * 64 + dd)) * SEQ + ii] = f2b(vv);
          }
        } else {
          float v = acc[mt][nt][r] + b0[n];
          if (mode == 1)      v += b2f(Rb[(size_t)m * N + n]);
          else if (mode == 2) v = fmaxf(v, 0.f) + tval * ttcW[n] + ttcb[n];
          if (mode == 3) Cf[(size_t)m * N + n] = v;
          else           Cb[(size_t)m * N + n] = f2b(v);
        }
      }
    }
  }
}

// ---------------------------------------------------------------------------
// LayerNorm over D=512 (bf16 in -> bf16 out), one row per block.
// ---------------------------------------------------------------------------
__global__ __launch_bounds__(256) void ln_kernel(
    const bf16u* __restrict__ X, const float* __restrict__ g,
    const float* __restrict__ bta, bf16u* __restrict__ Y)
{
  int row = blockIdx.x, tid = threadIdx.x;
  unsigned int pr = *(const unsigned int*)&X[(size_t)row * DMODEL + 2 * tid];
  float x0 = b2f((bf16u)(pr & 0xffff)), x1 = b2f((bf16u)(pr >> 16));
  __shared__ float red[8];
  int wv = tid >> 6, ln = tid & 63;
  float s = x0 + x1;
  for (int off = 32; off; off >>= 1) s += __shfl_xor(s, off);
  if (ln == 0) red[wv] = s;
  __syncthreads();
  float mu = (red[0] + red[1] + red[2] + red[3]) * (1.0f / DMODEL);
  float d0 = x0 - mu, d1 = x1 - mu;
  float vs = d0 * d0 + d1 * d1;
  for (int off = 32; off; off >>= 1) vs += __shfl_xor(vs, off);
  if (ln == 0) red[4 + wv] = vs;
  __syncthreads();
  float var = (red[4] + red[5] + red[6] + red[7]) * (1.0f / DMODEL);
  float rstd = rsqrtf(var + 1e-6f);
  float y0 = d0 * rstd * g[2 * tid]     + bta[2 * tid];
  float y1 = d1 * rstd * g[2 * tid + 1] + bta[2 * tid + 1];
  *(unsigned int*)&Y[(size_t)row * DMODEL + 2 * tid] = pack2(y0, y1);
}

// ---------------------------------------------------------------------------
__global__ __launch_bounds__(256) void tok_embed_kernel(
    const int* __restrict__ toks, const float* __restrict__ emb,
    const float* __restrict__ pos, bf16u* __restrict__ xb)
{
  int sp = blockIdx.x, b = blockIdx.y;
  int s = sp + NCOND;
  int tok = toks[b * S_TOK + sp];
  const float* er = emb + (size_t)tok * DMODEL;
  const float* pr = pos + (size_t)s * DMODEL;
  size_t ro = ((size_t)b * SEQ + s) * DMODEL;
  int d = threadIdx.x * 2;
  float v0 = er[d]     * 22.62741699796952f + pr[d];
  float v1 = er[d + 1] * 22.62741699796952f + pr[d + 1];
  *(unsigned int*)&xb[ro + d] = pack2(v0, v1);
}

// ---------------------------------------------------------------------------
__global__ __launch_bounds__(256) void cond_embed_kernel(
    const float* __restrict__ conds, const float* __restrict__ W1,
    const float* __restrict__ b1, const float* __restrict__ W2w,
    const float* __restrict__ b2, const float* __restrict__ nullc,
    const float* __restrict__ pos, bf16u* __restrict__ xb)
{
  int ci = blockIdx.x, b = blockIdx.y, tid = threadIdx.x;
  float c = conds[b * NCOND + ci];
  bool cn = isnan(c);
  float cm = cn ? 0.f : c;
  __shared__ float h1[DMODEL / 2];
  h1[tid] = fmaxf(cm * W1[ci * (DMODEL/2) + tid] + b1[ci * (DMODEL/2) + tid], 0.f);
  __syncthreads();
  for (int d = tid; d < DMODEL; d += 256) {
    float acc = b2[ci * DMODEL + d];
    for (int i = 0; i < DMODEL / 2; i++)
      acc = fmaf(h1[i], W2w[((size_t)ci * (DMODEL/2) + i) * DMODEL + d], acc);
    float ce = cn ? nullc[ci * DMODEL + d] : acc;
    xb[((size_t)b * SEQ + ci) * DMODEL + d] = f2b(ce + pos[(size_t)ci * DMODEL + d]);
  }
}

// ---------------------------------------------------------------------------
// E (fp32, all 6 layers) -> bf16.
// ---------------------------------------------------------------------------
__global__ __launch_bounds__(256) void e_conv_kernel(
    const float* __restrict__ E, bf16u* __restrict__ Eb)
{
  int i = (blockIdx.x * 256 + threadIdx.x) * 4;
  float4 v = *(const float4*)&E[i];
  ushort4 o;
  o.x = f2b(v.x); o.y = f2b(v.y); o.z = f2b(v.z); o.w = f2b(v.w);
  *(ushort4*)&Eb[i] = o;
}

// ---------------------------------------------------------------------------
// Split-K MFMA flash attention v7 = v4 (best measured: 84us) + Ps XOR-swizzle.
// v5/v6 pipelining post-mortem: both regressed (exposed-latency moved, not
// removed; v6's toks-after-prefetch forced vmcnt(0) mid-compute). Reverted.
// Ps swizzle: scalar P-writes were 4-way bank-conflicted (bank = 16*quad +
// l16/2); col ^= ((row>>2)&7)<<3 gives 2-lane/bank writes (free, m136) and
// keeps b128 reads balanced; octet-aligned XOR preserves s8frag contiguity.
// ---------------------------------------------------------------------------
#define PS_SWZ(row) ((((row) >> 2) & 7) << 3)

__global__ __launch_bounds__(256) void attn_part(
    const bf16u* __restrict__ Q, const bf16u* __restrict__ K,
    const bf16u* __restrict__ Vt_g, const bf16u* __restrict__ Eb16,
    const int* __restrict__ toks, bf16u* __restrict__ pacc,
    float* __restrict__ pstat)
{
  const int bid = blockIdx.x;
  const int g  = bid >> 7;              // (b,h)
  const int it = 31 - ((bid >> 2) & 31);// q-tile, heavy-first (LPT)
  const int c  = bid & 3;               // key chunk
  if (8 * c > it) return;
  const int slot = (g << 7) | (it << 2) | c;   // logical index for partials
  const int b = g >> 3, h = g & 7;
  const int i0 = it * 64;

  __shared__ bf16u Kb[64][72];          // K tile; becomes P after mid barrier
  __shared__ bf16u Vt[64][72];
  __shared__ bf16u Ebs[128][72];
  __shared__ float padv[64];
  bf16u (*Ps)[72] = Kb;                 // alias: disjoint lifetimes per step

  const int tid  = threadIdx.x;
  const int lane = tid & 63;
  const int wave = tid >> 6;
  const int quad = lane >> 4;
  const int l16  = lane & 15;

  const bf16u* qr = Q + ((size_t)(b * SEQ + i0 + wave * 16 + l16)) * DMODEL + h * DHEAD;
  s8frag q0 = *(const s8frag*)&qr[quad * 8];
  s8frag q1 = *(const s8frag*)&qr[32 + quad * 8];

  float m_run[4], l_run[4];
  f4frag acc[4];
#pragma unroll
  for (int r = 0; r < 4; r++) { m_run[r] = -1e30f; l_run[r] = 0.f; }
#pragma unroll
  for (int dt = 0; dt < 4; dt++) acc[dt] = (f4frag){0.f, 0.f, 0.f, 0.f};

  const int js0 = 8 * c;
  const int jsE = min(8 * c + 8, it + 1);
  const size_t vtbase = (size_t)(g * DHEAD) * SEQ;

  for (int js = js0; js < jsE; js++) {
    const int j0 = js * 64;
    const int m0 = 1984 - i0 + j0;   // E row of band col 0
    __syncthreads();

    // K tile (2 x uint4 / thread)
#pragma unroll
    for (int e = 0; e < 2; e++) {
      int cc = e * 256 + tid;
      int jr = cc >> 3, doff = (cc & 7) * 8;
      *(uint4*)&Kb[jr][doff] =
          *(const uint4*)&K[((size_t)(b * SEQ + j0 + jr)) * DMODEL + h * DHEAD + doff];
    }
    // V^T tile from pre-transposed global (2 x uint4 / thread)
#pragma unroll
    for (int e = 0; e < 2; e++) {
      int cc = e * 256 + tid;
      int dr = cc >> 3, joff = (cc & 7) * 8;
      *(uint4*)&Vt[dr][joff] =
          *(const uint4*)&Vt_g[vtbase + (size_t)dr * SEQ + j0 + joff];
    }
    // E ring: first step fill 128 rows, then 64 new rows
    if (js == js0) {
#pragma unroll
      for (int e = 0; e < 4; e++) {
        int cc = e * 256 + tid;
        int er = cc >> 3, doff = (cc & 7) * 8;
        int m = m0 + er; int row = m > SEQ - 1 ? SEQ - 1 : m;
        *(uint4*)&Ebs[m & 127][doff] = *(const uint4*)&Eb16[(size_t)row * DHEAD + doff];
      }
    } else {
#pragma unroll
      for (int e = 0; e < 2; e++) {
        int cc = e * 256 + tid;
        int er = 64 + (cc >> 3), doff = (cc & 7) * 8;
        int m = m0 + er; int row = m > SEQ - 1 ? SEQ - 1 : m;
        *(uint4*)&Ebs[m & 127][doff] = *(const uint4*)&Eb16[(size_t)row * DHEAD + doff];
      }
    }
    if (tid < 64) {
      int j = j0 + tid;
      bool pad = (j >= NCOND) && (toks[b * S_TOK + j - NCOND] == 0);
      padv[tid] = pad ? -1e30f : 0.f;
    }
    __syncthreads();

    // QK^T (reads Kb)
    f4frag sc[4];
#pragma unroll
    for (int nt = 0; nt < 4; nt++) {
      s8frag k0 = *(const s8frag*)&Kb[nt * 16 + l16][quad * 8];
      s8frag k1 = *(const s8frag*)&Kb[nt * 16 + l16][32 + quad * 8];
      f4frag cc = (f4frag){0.f, 0.f, 0.f, 0.f};
      cc = __builtin_amdgcn_mfma_f32_16x16x32_bf16(q0, k0, cc, 0, 0, 0);
      cc = __builtin_amdgcn_mfma_f32_16x16x32_bf16(q1, k1, cc, 0, 0, 0);
      sc[nt] = cc;
    }

    // QE: 5 frags covering band cols [(3-wave)*16, (8-wave)*16)  (reads Ebs)
    f4frag qef[5];
#pragma unroll
    for (int f = 0; f < 5; f++) {
      int ct = f + 3 - wave;
      int m = m0 + ct * 16 + l16;
      const bf16u* erow = &Ebs[m & 127][0];
      s8frag e0 = *(const s8frag*)&erow[quad * 8];
      s8frag e1 = *(const s8frag*)&erow[32 + quad * 8];
      f4frag cc = (f4frag){0.f, 0.f, 0.f, 0.f};
      cc = __builtin_amdgcn_mfma_f32_16x16x32_bf16(q0, e0, cc, 0, 0, 0);
      cc = __builtin_amdgcn_mfma_f32_16x16x32_bf16(q1, e1, cc, 0, 0, 0);
      qef[f] = cc;
    }

    // All Kb/Ebs reads are drained by this barrier; Kb becomes the P buffer.
    __syncthreads();

    float pvv[4];
#pragma unroll
    for (int nt = 0; nt < 4; nt++) pvv[nt] = padv[nt * 16 + l16];

    // scores + online softmax; QE gathered by ONE shuffle (select at source).
    float s[4][4], mx[4];
#pragma unroll
    for (int r = 0; r < 4; r++) {
      int rloc = wave * 16 + quad * 4 + r;
      int ig = i0 + rloc;
      int t = quad * 4 + r;
      int v = 63 - 16 * wave + l16 - t;
      int srcl = (lane & 48) | (v & 15);
      bool hiSrc = (l16 < 15 - t);     // target hi <=> this at source lane
#pragma unroll
      for (int nt = 0; nt < 4; nt++) {
        float pre = hiSrc ? qef[nt + 1][r] : qef[nt][r];
        float qe = __shfl(pre, srcl);
        int jl = nt * 16 + l16;
        float sv = (sc[nt][r] + qe) * 0.125f + pvv[nt];
        if (j0 + jl > ig) sv = -1e30f;
        s[nt][r] = sv;
      }
      float m = fmaxf(fmaxf(s[0][r], s[1][r]), fmaxf(s[2][r], s[3][r]));
      float tr;
      DPP_ROR(tr, m, 1); m = fmaxf(m, tr);
      DPP_ROR(tr, m, 2); m = fmaxf(m, tr);
      DPP_ROR(tr, m, 4); m = fmaxf(m, tr);
      DPP_ROR(tr, m, 8); m = fmaxf(m, tr);
      mx[r] = m;
    }
    float alpha[4];
#pragma unroll
    for (int r = 0; r < 4; r++) {
      float m_new = fmaxf(m_run[r], mx[r]);
      alpha[r] = __expf(m_run[r] - m_new);
      float psum = 0.f;
      int rloc = wave * 16 + quad * 4 + r;
#pragma unroll
      for (int nt = 0; nt < 4; nt++) {
        float p = __expf(s[nt][r] - m_new);
        Ps[rloc][(nt * 16 + l16) ^ PS_SWZ(rloc)] = f2b(p);
        psum += p;
      }
      float tr;
      DPP_ROR(tr, psum, 1); psum += tr;
      DPP_ROR(tr, psum, 2); psum += tr;
      DPP_ROR(tr, psum, 4); psum += tr;
      DPP_ROR(tr, psum, 8); psum += tr;
      l_run[r] = l_run[r] * alpha[r] + psum;
      m_run[r] = m_new;
    }
#pragma unroll
    for (int dt = 0; dt < 4; dt++)
#pragma unroll
      for (int r = 0; r < 4; r++) acc[dt][r] *= alpha[r];

    // P @ V  (Ps rows are wave-local; swizzled reads match swizzled writes)
    {
      int prow = wave * 16 + l16;
      int psw = PS_SWZ(prow);
      s8frag p0 = *(const s8frag*)&Ps[prow][(quad * 8) ^ psw];
      s8frag p1 = *(const s8frag*)&Ps[prow][(32 + quad * 8) ^ psw];
#pragma unroll
      for (int dt = 0; dt < 4; dt++) {
        s8frag v0 = *(const s8frag*)&Vt[dt * 16 + l16][quad * 8];
        s8frag v1 = *(const s8frag*)&Vt[dt * 16 + l16][32 + quad * 8];
        acc[dt] = __builtin_amdgcn_mfma_f32_16x16x32_bf16(p0, v0, acc[dt], 0, 0, 0);
        acc[dt] = __builtin_amdgcn_mfma_f32_16x16x32_bf16(p1, v1, acc[dt], 0, 0, 0);
      }
    }
  }

  // write partials (indexed by logical slot, not blockIdx)
#pragma unroll
  for (int r = 0; r < 4; r++) {
    int rloc = wave * 16 + quad * 4 + r;
    if (l16 == 0) {
      pstat[(size_t)slot * 128 + rloc]      = m_run[r];
      pstat[(size_t)slot * 128 + 64 + rloc] = l_run[r];
    }
#pragma unroll
    for (int dt = 0; dt < 4; dt++)
      pacc[(size_t)slot * 4096 + rloc * 64 + dt * 16 + l16] = f2b(acc[dt][r]);
  }
}

// ---------------------------------------------------------------------------
// Merge <=4 chunk partials per (b,h,q-tile); write O (bf16) into qb.
// ---------------------------------------------------------------------------
__global__ __launch_bounds__(256) void attn_combine(
    const bf16u* __restrict__ pacc, const float* __restrict__ pstat,
    bf16u* __restrict__ O)
{
  int bid = blockIdx.x;             // g*32 + it
  int g = bid >> 5, it = bid & 31;
  int b = g >> 3, h = g & 7;
  int i0 = it * 64;
  int nc = (it >> 3) + 1;
  int tid = threadIdx.x;
  int row = tid >> 2, ql = tid & 3;

  float m_tot = -1e30f;
  float mc[4], lc[4];
#pragma unroll
  for (int c = 0; c < 4; c++) {
    if (c < nc) {
      size_t pb = (size_t)(bid * 4 + c) * 128;
      mc[c] = pstat[pb + row];
      lc[c] = pstat[pb + 64 + row];
      m_tot = fmaxf(m_tot, mc[c]);
    }
  }
  float l_tot = 0.f, w[4];
#pragma unroll
  for (int c = 0; c < 4; c++) {
    if (c < nc) { w[c] = __expf(mc[c] - m_tot); l_tot += w[c] * lc[c]; }
    else w[c] = 0.f;
  }
  float inv = 1.0f / l_tot;

  float out[16];
#pragma unroll
  for (int k = 0; k < 16; k++) out[k] = 0.f;
#pragma unroll
  for (int c = 0; c < 4; c++) {
    if (c >= nc) break;
    const bf16u* pa = pacc + (size_t)(bid * 4 + c) * 4096 + row * 64 + ql * 16;
#pragma unroll
    for (int k = 0; k < 16; k++) out[k] += w[c] * b2f(pa[k]);
  }
  bf16u* ob = O + ((size_t)(b * SEQ + i0 + row)) * DMODEL + h * DHEAD + ql * 16;
#pragma unroll
  for (int k = 0; k < 16; k++) ob[k] = f2b(out[k] * inv);
}

// ---------------------------------------------------------------------------
extern "C" void kernel_launch(void* const* d_in, const int* in_sizes, int n_in,
                              void* d_out, int out_size, void* d_ws, size_t ws_size,
                              hipStream_t stream) {
  const int*   toks  = (const int*)  d_in[0];
  const float* conds = (const float*)d_in[1];
  const float* ttc   = (const float*)d_in[2];
  const float* emb   = (const float*)d_in[3];
  const float* pos   = (const float*)d_in[4];
  const float* cW1   = (const float*)d_in[5];
  const float* cb1   = (const float*)d_in[6];
  const float* cW2   = (const float*)d_in[7];
  const float* cb2   = (const float*)d_in[8];
  const float* nullc = (const float*)d_in[9];
  const float* ttcW  = (const float*)d_in[10];
  const float* ttcb  = (const float*)d_in[11];
  const float* Wq    = (const float*)d_in[12];
  const float* Wk    = (const float*)d_in[13];
  const float* Wv    = (const float*)d_in[14];
  const float* Wo    = (const float*)d_in[15];
  const float* bq    = (const float*)d_in[16];
  const float* bk    = (const float*)d_in[17];
  const float* bv    = (const float*)d_in[18];
  const float* bo    = (const float*)d_in[19];
  const float* E     = (const float*)d_in[20];
  const float* fW1   = (const float*)d_in[21];
  const float* fb1   = (const float*)d_in[22];
  const float* fW2   = (const float*)d_in[23];
  const float* fb2   = (const float*)d_in[24];
  const float* ln1g  = (const float*)d_in[25];
  const float* ln1b  = (const float*)d_in[26];
  const float* ln2g  = (const float*)d_in[27];
  const float* ln2b  = (const float*)d_in[28];
  const float* fcW   = (const float*)d_in[29];
  const float* fcb   = (const float*)d_in[30];

  const size_t MB1 = 1024 * 1024;
  const size_t MD = (size_t)MROWS * DMODEL;
  char* p = (char*)d_ws;
  bf16u* xb    = (bf16u*)p; p += 4 * MB1;
  bf16u* qkvb  = (bf16u*)p; p += 12 * MB1;   // qb | kb | vb(unused as linear V)
  bf16u* hidb  = (bf16u*)p; p += 16 * MB1;   // FFN hidden / pacc alias
  float* pstat = (float*)p; p += 1 * MB1;
  bf16u* vbt   = (bf16u*)p; p += 4 * MB1;    // V transposed (written by QKV GEMM)
  bf16u* ebf   = (bf16u*)p; p += 1536 * 1024;   // E bf16, 6 layers
  bf16u* WqkvT = (bf16u*)p; p += 9 * MB1;
  bf16u* WoT   = (bf16u*)p; p += 3 * MB1;
  bf16u* W1T   = (bf16u*)p; p += 12 * MB1;
  bf16u* W2T   = (bf16u*)p; p += 12 * MB1;
  bf16u* fcT   = (bf16u*)p; p += 512 * 1024;    // total 75 MB
  bf16u* qb = qkvb;
  bf16u* kb = qkvb + MD;        // out1b aliases kb (disjoint lifetimes)
  bf16u* vb = qkvb + 2 * MD;    // t1b aliases vb (disjoint lifetimes)
  bf16u* out1b = kb;
  bf16u* t1b   = vb;
  bf16u* pacc  = hidb;

  // ---- setup: embeds + all-layer weight transposes + E conversion ----
  cond_embed_kernel<<<dim3(NCOND, BATCH), 256, 0, stream>>>(
      conds, cW1, cb1, cW2, cb2, nullc, pos, xb);
  tok_embed_kernel<<<dim3(S_TOK, BATCH), 256, 0, stream>>>(toks, emb, pos, xb);
  wt_all_kernel<<<6 * 768 + 64, 256, 0, stream>>>(Wq, Wk, Wv, Wo, fW1, fW2, fcW,
      WqkvT, WoT, W1T, W2T, fcT);
  e_conv_kernel<<<(NLAYER * SEQ * DHEAD) / 1024, 256, 0, stream>>>(E, ebf);

  dim3 gQKV(MROWS / 128, 1536 / 128);      // (32,12)
  dim3 gFF1(MROWS / 128, DINNER / 128);    // (32,16)
  dim3 gN512(MROWS / 32, DMODEL / 128);    // (128,4): 512 blocks, RB=1

  for (int l = 0; l < NLAYER; l++) {
    // fused QKV; V slice written transposed into vbt (vt_kernel fused away)
    mgemm<4><<<gQKV, 256, 0, stream>>>(xb, WqkvT + (size_t)l * 786432,
        bq + l * DMODEL, bk + l * DMODEL, bv + l * DMODEL, nullptr,
        (float*)vbt, qkvb, MROWS, 1536, DMODEL, 4, nullptr, nullptr, nullptr);

    attn_part<<<2048, 256, 0, stream>>>(qb, kb, vbt,
        ebf + (size_t)l * SEQ * DHEAD, toks, pacc, pstat);
    attn_combine<<<512, 256, 0, stream>>>(pacc, pstat, qb);

    // t1 = attn @ Wo + bo + x
    mgemm<1><<<gN512, 256, 0, stream>>>(qb, WoT + (size_t)l * 262144,
        bo + l * DMODEL, nullptr, nullptr, xb,
        nullptr, t1b, MROWS, DMODEL, DMODEL, 1, nullptr, nullptr, nullptr);
    ln_kernel<<<MROWS, 256, 0, stream>>>(t1b, ln1g + l * DMODEL, ln1b + l * DMODEL,
        out1b);

    // hid = relu(out1 @ W1 + b1) + chord
    mgemm<4><<<gFF1, 256, 0, stream>>>(out1b, W1T + (size_t)l * 1048576,
        fb1 + l * DINNER, nullptr, nullptr, nullptr,
        nullptr, hidb, MROWS, DINNER, DMODEL, 2, ttc, ttcW, ttcb);
    // t1 = hid @ W2 + b2 + out1
    mgemm<1><<<gN512, 256, 0, stream>>>(hidb, W2T + (size_t)l * 1048576,
        fb2 + l * DMODEL, nullptr, nullptr, out1b,
        nullptr, t1b, MROWS, DMODEL, DINNER, 1, nullptr, nullptr, nullptr);
    ln_kernel<<<MROWS, 256, 0, stream>>>(t1b, ln2g + l * DMODEL, ln2b + l * DMODEL,
        xb);
  }

  // logits = x @ fc_W + fc_b (fp32 out)
  mgemm<1><<<gN512, 256, 0, stream>>>(xb, fcT,
      fcb, nullptr, nullptr, nullptr,
      (float*)d_out, nullptr, MROWS, VOCAB, DMODEL, 3, nullptr, nullptr, nullptr);
}

// Round 6
// 1466.542 us; speedup vs baseline: 1.3356x; 1.0608x over previous
//
#include <hip/hip_runtime.h>
#include <hip/hip_bf16.h>
#include <math.h>

// ---- problem constants ----
#define BATCH  2
#define S_TOK  2046
#define NCOND  2
#define SEQ    2048
#define DMODEL 512
#define DINNER 2048
#define NHEAD  8
#define DHEAD  64
#define NLAYER 6
#define VOCAB  512
#define MROWS  (BATCH*SEQ)   // 4096 rows

typedef unsigned short bf16u;
typedef __attribute__((ext_vector_type(8))) short s8frag;   // 8 bf16 (4 VGPRs)
typedef __attribute__((ext_vector_type(4))) float f4frag;   // 4 fp32 acc

__device__ __forceinline__ float b2f(bf16u u) {
  union { unsigned int i; float f; } v; v.i = ((unsigned int)u) << 16; return v.f;
}
__device__ __forceinline__ bf16u f2b(float f) {
  union { float f; unsigned int i; } v; v.f = f;
  unsigned int x = v.i;
  return (bf16u)((x + 0x7fffu + ((x >> 16) & 1u)) >> 16);
}
__device__ __forceinline__ unsigned int pack2(float a, float b) {
  return (unsigned int)f2b(a) | ((unsigned int)f2b(b) << 16);
}

// async global->LDS, 16B per lane. LDS dest must be wave-uniform base +
// lane*16 (we pass per-lane ptrs that satisfy exactly that).
__device__ __forceinline__ void gld16(const bf16u* g, bf16u* l) {
  __builtin_amdgcn_global_load_lds(
      (const __attribute__((address_space(1))) unsigned int*)g,
      (__attribute__((address_space(3))) unsigned int*)l,
      16, 0, 0);
}

// DPP row-rotate (within 16-lane row) — VALU-pipe lane exchange, not LDS.
#define DPP_ROR(dst, src, N)                                              \
  dst = __int_as_float(__builtin_amdgcn_update_dpp(                       \
      0, __float_as_int(src), 0x120 + (N), 0xF, 0xF, true))

// ---------------------------------------------------------------------------
// All-layer weight transpose + bf16: dst[N][K] = src[K][N]. One launch.
// blocks: 6 layers x 768 (q64|k64|v64|o64|W1 256|W2 256) + 64 (fc) = 4672.
// ---------------------------------------------------------------------------
__global__ __launch_bounds__(256) void wt_all_kernel(
    const float* __restrict__ Wq, const float* __restrict__ Wk,
    const float* __restrict__ Wv, const float* __restrict__ Wo,
    const float* __restrict__ W1, const float* __restrict__ W2,
    const float* __restrict__ fcW,
    bf16u* __restrict__ qkvT, bf16u* __restrict__ oT,
    bf16u* __restrict__ w1T, bf16u* __restrict__ w2T, bf16u* __restrict__ fcT)
{
  int bid = blockIdx.x;
  const float* src; bf16u* dst; int N, K, kt, nt;
  if (bid < 6 * 768) {
    int L = bid / 768, t = bid - L * 768;
    if (t < 256) {
      int mat = t >> 6, tt = t & 63;
      const float* s4[4] = {Wq, Wk, Wv, Wo};
      src = s4[mat] + (size_t)L * DMODEL * DMODEL;
      dst = (mat < 3) ? (qkvT + (size_t)L * 786432 + (size_t)mat * 262144)
                      : (oT + (size_t)L * 262144);
      K = DMODEL; N = DMODEL; kt = tt >> 3; nt = tt & 7;
    } else if (t < 512) {
      int tt = t - 256;
      src = W1 + (size_t)L * DMODEL * DINNER; dst = w1T + (size_t)L * 1048576;
      K = DMODEL; N = DINNER; kt = tt >> 5; nt = tt & 31;
    } else {
      int tt = t - 512;
      src = W2 + (size_t)L * DINNER * DMODEL; dst = w2T + (size_t)L * 1048576;
      K = DINNER; N = DMODEL; kt = tt >> 3; nt = tt & 7;
    }
  } else {
    int tt = bid - 6 * 768;
    src = fcW; dst = fcT;
    K = DMODEL; N = VOCAB; kt = tt >> 3; nt = tt & 7;
  }
  __shared__ bf16u Ls[64][66];
  int tid = threadIdx.x;
  int c = tid & 63, r4 = tid >> 6;
#pragma unroll
  for (int i = 0; i < 16; i++) {
    int r = i * 4 + r4;
    Ls[r][c] = f2b(src[(size_t)(kt * 64 + r) * N + nt * 64 + c]);
  }
  __syncthreads();
#pragma unroll
  for (int i = 0; i < 16; i++) {
    int rr = i * 4 + r4;
    dst[(size_t)(nt * 64 + rr) * K + kt * 64 + c] = Ls[c][rr];
  }
}

// ---------------------------------------------------------------------------
// V transpose (bf16): vb[(b,i)][h*64+d] -> vbt[(b*8+h)*64+d][i]. 512 blocks.
// ---------------------------------------------------------------------------
__global__ __launch_bounds__(256) void vt_kernel(
    const bf16u* __restrict__ vb, bf16u* __restrict__ vbt)
{
  int bid = blockIdx.x;
  int b = bid >> 8, t = bid & 255;
  int it = t >> 3, h = t & 7;
  __shared__ bf16u Ls[64][66];
  int tid = threadIdx.x;
  int c = tid & 63, r4 = tid >> 6;
#pragma unroll
  for (int i = 0; i < 16; i++) {
    int r = i * 4 + r4;
    Ls[r][c] = vb[(size_t)(b * SEQ + it * 64 + r) * DMODEL + h * DHEAD + c];
  }
  __syncthreads();
#pragma unroll
  for (int i = 0; i < 16; i++) {
    int rr = i * 4 + r4;
    vbt[(size_t)((b * 8 + h) * DHEAD + rr) * SEQ + it * 64 + c] = Ls[c][rr];
  }
}

// ---------------------------------------------------------------------------
// MFMA GEMM, RB m-tiles/wave (4 -> 128x128, 2 -> 64x128, 1 -> 32x128).
// Staging via global_load_lds (async DMA, no VGPR round-trip): LDS tiles are
// LINEAR (no pad) so lane i's dest = base + i*16B; fragment reads verified
// bank-balanced (8 bank-cycles = minimum) in the linear layout.
// modes: 0 +bias->bf16 ; 1 +bias+Rb(bf16)->bf16 ; 2 relu(+bias)+chord->bf16 ;
//        3 +bias->fp32 ; 4 fused-QKV routing -> bf16 (3 slices)
// ---------------------------------------------------------------------------
template <int RB>
__global__ __launch_bounds__(256) void mgemm(
    const bf16u* __restrict__ A, const bf16u* __restrict__ Wt,
    const float* __restrict__ b0, const float* __restrict__ b1,
    const float* __restrict__ b2, const bf16u* __restrict__ Rb,
    float* __restrict__ Cf, bf16u* __restrict__ Cb,
    int M, int N, int K, int mode,
    const float* __restrict__ ttc, const float* __restrict__ ttcW,
    const float* __restrict__ ttcb)
{
  __shared__ bf16u Ab[RB * 32][32];
  __shared__ bf16u Bb[128][32];
  const int tid = threadIdx.x;
  const int lane = tid & 63, wave = tid >> 6;
  const int quad = lane >> 4, l16 = lane & 15;
  const int wm = wave >> 1, wn = wave & 1;
  const int row0 = blockIdx.x * (RB * 32), col0 = blockIdx.y * 128;

  f4frag acc[RB][4];
#pragma unroll
  for (int i = 0; i < RB; i++)
#pragma unroll
    for (int j = 0; j < 4; j++) acc[i][j] = (f4frag){0.f, 0.f, 0.f, 0.f};

  for (int k0 = 0; k0 < K; k0 += 32) {
    if (k0) __syncthreads();
    // A tile: RB*128 chunks of 16B, chunk -> row=chunk>>2, koff=(chunk&3)*8
    if constexpr (RB >= 2) {
#pragma unroll
      for (int i = 0; i < RB / 2; i++) {
        int chunk = i * 256 + tid;
        int r = chunk >> 2, q = chunk & 3;
        gld16(&A[(size_t)(row0 + r) * K + k0 + q * 8], &Ab[0][0] + chunk * 8);
      }
    } else {
      if (tid < 128) {
        int r = tid >> 2, q = tid & 3;
        gld16(&A[(size_t)(row0 + r) * K + k0 + q * 8], &Ab[0][0] + tid * 8);
      }
    }
    // B tile: 512 chunks
#pragma unroll
    for (int i = 0; i < 2; i++) {
      int chunk = i * 256 + tid;
      int r = chunk >> 2, q = chunk & 3;
      gld16(&Wt[(size_t)(col0 + r) * K + k0 + q * 8], &Bb[0][0] + chunk * 8);
    }
    __syncthreads();   // compiler drains vmcnt before s_barrier
    s8frag af[RB], bfr[4];
#pragma unroll
    for (int t = 0; t < RB; t++)
      af[t] = *(const s8frag*)&Ab[wm * (RB * 16) + t * 16 + l16][quad * 8];
#pragma unroll
    for (int t = 0; t < 4; t++)
      bfr[t] = *(const s8frag*)&Bb[wn * 64 + t * 16 + l16][quad * 8];
#pragma unroll
    for (int mt = 0; mt < RB; mt++)
#pragma unroll
      for (int nt = 0; nt < 4; nt++)
        acc[mt][nt] = __builtin_amdgcn_mfma_f32_16x16x32_bf16(
            af[mt], bfr[nt], acc[mt][nt], 0, 0, 0);
  }

#pragma unroll
  for (int mt = 0; mt < RB; mt++) {
#pragma unroll
    for (int r = 0; r < 4; r++) {
      int m = row0 + wm * (RB * 16) + mt * 16 + quad * 4 + r;
      float tval = 0.f;
      if (mode == 2) {
        int bb = m >> 11, s = m & (SEQ - 1);
        int sp = (s < NCOND) ? 0 : (s - NCOND);
        tval = 8.0f - ttc[bb * S_TOK + sp];
      }
#pragma unroll
      for (int nt = 0; nt < 4; nt++) {
        int n = col0 + wn * 64 + nt * 16 + l16;
        if (mode == 4) {
          int sel = n >> 9, nn = n & 511;
          float bv = (sel == 0) ? b0[nn] : ((sel == 1) ? b1[nn] : b2[nn]);
          Cb[(size_t)sel * MROWS * DMODEL + (size_t)m * DMODEL + nn]
              = f2b(acc[mt][nt][r] + bv);
        } else {
          float v = acc[mt][nt][r] + b0[n];
          if (mode == 1)      v += b2f(Rb[(size_t)m * N + n]);
          else if (mode == 2) v = fmaxf(v, 0.f) + tval * ttcW[n] + ttcb[n];
          if (mode == 3) Cf[(size_t)m * N + n] = v;
          else           Cb[(size_t)m * N + n] = f2b(v);
        }
      }
    }
  }
}

// ---------------------------------------------------------------------------
// LayerNorm over D=512 (bf16 in -> bf16 out), one row per block.
// ---------------------------------------------------------------------------
__global__ __launch_bounds__(256) void ln_kernel(
    const bf16u* __restrict__ X, const float* __restrict__ g,
    const float* __restrict__ bta, bf16u* __restrict__ Y)
{
  int row = blockIdx.x, tid = threadIdx.x;
  unsigned int pr = *(const unsigned int*)&X[(size_t)row * DMODEL + 2 * tid];
  float x0 = b2f((bf16u)(pr & 0xffff)), x1 = b2f((bf16u)(pr >> 16));
  __shared__ float red[8];
  int wv = tid >> 6, ln = tid & 63;
  float s = x0 + x1;
  for (int off = 32; off; off >>= 1) s += __shfl_xor(s, off);
  if (ln == 0) red[wv] = s;
  __syncthreads();
  float mu = (red[0] + red[1] + red[2] + red[3]) * (1.0f / DMODEL);
  float d0 = x0 - mu, d1 = x1 - mu;
  float vs = d0 * d0 + d1 * d1;
  for (int off = 32; off; off >>= 1) vs += __shfl_xor(vs, off);
  if (ln == 0) red[4 + wv] = vs;
  __syncthreads();
  float var = (red[4] + red[5] + red[6] + red[7]) * (1.0f / DMODEL);
  float rstd = rsqrtf(var + 1e-6f);
  float y0 = d0 * rstd * g[2 * tid]     + bta[2 * tid];
  float y1 = d1 * rstd * g[2 * tid + 1] + bta[2 * tid + 1];
  *(unsigned int*)&Y[(size_t)row * DMODEL + 2 * tid] = pack2(y0, y1);
}

// ---------------------------------------------------------------------------
__global__ __launch_bounds__(256) void tok_embed_kernel(
    const int* __restrict__ toks, const float* __restrict__ emb,
    const float* __restrict__ pos, bf16u* __restrict__ xb)
{
  int sp = blockIdx.x, b = blockIdx.y;
  int s = sp + NCOND;
  int tok = toks[b * S_TOK + sp];
  const float* er = emb + (size_t)tok * DMODEL;
  const float* pr = pos + (size_t)s * DMODEL;
  size_t ro = ((size_t)b * SEQ + s) * DMODEL;
  int d = threadIdx.x * 2;
  float v0 = er[d]     * 22.62741699796952f + pr[d];
  float v1 = er[d + 1] * 22.62741699796952f + pr[d + 1];
  *(unsigned int*)&xb[ro + d] = pack2(v0, v1);
}

// ---------------------------------------------------------------------------
__global__ __launch_bounds__(256) void cond_embed_kernel(
    const float* __restrict__ conds, const float* __restrict__ W1,
    const float* __restrict__ b1, const float* __restrict__ W2w,
    const float* __restrict__ b2, const float* __restrict__ nullc,
    const float* __restrict__ pos, bf16u* __restrict__ xb)
{
  int ci = blockIdx.x, b = blockIdx.y, tid = threadIdx.x;
  float c = conds[b * NCOND + ci];
  bool cn = isnan(c);
  float cm = cn ? 0.f : c;
  __shared__ float h1[DMODEL / 2];
  h1[tid] = fmaxf(cm * W1[ci * (DMODEL/2) + tid] + b1[ci * (DMODEL/2) + tid], 0.f);
  __syncthreads();
  for (int d = tid; d < DMODEL; d += 256) {
    float acc = b2[ci * DMODEL + d];
    for (int i = 0; i < DMODEL / 2; i++)
      acc = fmaf(h1[i], W2w[((size_t)ci * (DMODEL/2) + i) * DMODEL + d], acc);
    float ce = cn ? nullc[ci * DMODEL + d] : acc;
    xb[((size_t)b * SEQ + ci) * DMODEL + d] = f2b(ce + pos[(size_t)ci * DMODEL + d]);
  }
}

// ---------------------------------------------------------------------------
// E (fp32, all 6 layers) -> bf16.
// ---------------------------------------------------------------------------
__global__ __launch_bounds__(256) void e_conv_kernel(
    const float* __restrict__ E, bf16u* __restrict__ Eb)
{
  int i = (blockIdx.x * 256 + threadIdx.x) * 4;
  float4 v = *(const float4*)&E[i];
  ushort4 o;
  o.x = f2b(v.x); o.y = f2b(v.y); o.z = f2b(v.z); o.w = f2b(v.w);
  *(ushort4*)&Eb[i] = o;
}

// ---------------------------------------------------------------------------
// Split-K MFMA flash attention (v4 structure, measured 83us; attn left alone).
// ---------------------------------------------------------------------------
#define PS_SWZ(row) ((((row) >> 2) & 7) << 3)

__global__ __launch_bounds__(256) void attn_part(
    const bf16u* __restrict__ Q, const bf16u* __restrict__ K,
    const bf16u* __restrict__ Vt_g, const bf16u* __restrict__ Eb16,
    const int* __restrict__ toks, bf16u* __restrict__ pacc,
    float* __restrict__ pstat)
{
  const int bid = blockIdx.x;
  const int g  = bid >> 7;              // (b,h)
  const int it = 31 - ((bid >> 2) & 31);// q-tile, heavy-first (LPT)
  const int c  = bid & 3;               // key chunk
  if (8 * c > it) return;
  const int slot = (g << 7) | (it << 2) | c;   // logical index for partials
  const int b = g >> 3, h = g & 7;
  const int i0 = it * 64;

  __shared__ bf16u Kb[64][72];          // K tile; becomes P after mid barrier
  __shared__ bf16u Vt[64][72];
  __shared__ bf16u Ebs[128][72];
  __shared__ float padv[64];
  bf16u (*Ps)[72] = Kb;                 // alias: disjoint lifetimes per step

  const int tid  = threadIdx.x;
  const int lane = tid & 63;
  const int wave = tid >> 6;
  const int quad = lane >> 4;
  const int l16  = lane & 15;

  const bf16u* qr = Q + ((size_t)(b * SEQ + i0 + wave * 16 + l16)) * DMODEL + h * DHEAD;
  s8frag q0 = *(const s8frag*)&qr[quad * 8];
  s8frag q1 = *(const s8frag*)&qr[32 + quad * 8];

  float m_run[4], l_run[4];
  f4frag acc[4];
#pragma unroll
  for (int r = 0; r < 4; r++) { m_run[r] = -1e30f; l_run[r] = 0.f; }
#pragma unroll
  for (int dt = 0; dt < 4; dt++) acc[dt] = (f4frag){0.f, 0.f, 0.f, 0.f};

  const int js0 = 8 * c;
  const int jsE = min(8 * c + 8, it + 1);
  const size_t vtbase = (size_t)(g * DHEAD) * SEQ;

  for (int js = js0; js < jsE; js++) {
    const int j0 = js * 64;
    const int m0 = 1984 - i0 + j0;   // E row of band col 0
    __syncthreads();

    // K tile (2 x uint4 / thread)
#pragma unroll
    for (int e = 0; e < 2; e++) {
      int cc = e * 256 + tid;
      int jr = cc >> 3, doff = (cc & 7) * 8;
      *(uint4*)&Kb[jr][doff] =
          *(const uint4*)&K[((size_t)(b * SEQ + j0 + jr)) * DMODEL + h * DHEAD + doff];
    }
    // V^T tile from pre-transposed global (2 x uint4 / thread)
#pragma unroll
    for (int e = 0; e < 2; e++) {
      int cc = e * 256 + tid;
      int dr = cc >> 3, joff = (cc & 7) * 8;
      *(uint4*)&Vt[dr][joff] =
          *(const uint4*)&Vt_g[vtbase + (size_t)dr * SEQ + j0 + joff];
    }
    // E ring: first step fill 128 rows, then 64 new rows
    if (js == js0) {
#pragma unroll
      for (int e = 0; e < 4; e++) {
        int cc = e * 256 + tid;
        int er = cc >> 3, doff = (cc & 7) * 8;
        int m = m0 + er; int row = m > SEQ - 1 ? SEQ - 1 : m;
        *(uint4*)&Ebs[m & 127][doff] = *(const uint4*)&Eb16[(size_t)row * DHEAD + doff];
      }
    } else {
#pragma unroll
      for (int e = 0; e < 2; e++) {
        int cc = e * 256 + tid;
        int er = 64 + (cc >> 3), doff = (cc & 7) * 8;
        int m = m0 + er; int row = m > SEQ - 1 ? SEQ - 1 : m;
        *(uint4*)&Ebs[m & 127][doff] = *(const uint4*)&Eb16[(size_t)row * DHEAD + doff];
      }
    }
    if (tid < 64) {
      int j = j0 + tid;
      bool pad = (j >= NCOND) && (toks[b * S_TOK + j - NCOND] == 0);
      padv[tid] = pad ? -1e30f : 0.f;
    }
    __syncthreads();

    // QK^T (reads Kb)
    f4frag sc[4];
#pragma unroll
    for (int nt = 0; nt < 4; nt++) {
      s8frag k0 = *(const s8frag*)&Kb[nt * 16 + l16][quad * 8];
      s8frag k1 = *(const s8frag*)&Kb[nt * 16 + l16][32 + quad * 8];
      f4frag cc = (f4frag){0.f, 0.f, 0.f, 0.f};
      cc = __builtin_amdgcn_mfma_f32_16x16x32_bf16(q0, k0, cc, 0, 0, 0);
      cc = __builtin_amdgcn_mfma_f32_16x16x32_bf16(q1, k1, cc, 0, 0, 0);
      sc[nt] = cc;
    }

    // QE: 5 frags covering band cols [(3-wave)*16, (8-wave)*16)  (reads Ebs)
    f4frag qef[5];
#pragma unroll
    for (int f = 0; f < 5; f++) {
      int ct = f + 3 - wave;
      int m = m0 + ct * 16 + l16;
      const bf16u* erow = &Ebs[m & 127][0];
      s8frag e0 = *(const s8frag*)&erow[quad * 8];
      s8frag e1 = *(const s8frag*)&erow[32 + quad * 8];
      f4frag cc = (f4frag){0.f, 0.f, 0.f, 0.f};
      cc = __builtin_amdgcn_mfma_f32_16x16x32_bf16(q0, e0, cc, 0, 0, 0);
      cc = __builtin_amdgcn_mfma_f32_16x16x32_bf16(q1, e1, cc, 0, 0, 0);
      qef[f] = cc;
    }

    // All Kb/Ebs reads are drained by this barrier; Kb becomes the P buffer.
    __syncthreads();

    float pvv[4];
#pragma unroll
    for (int nt = 0; nt < 4; nt++) pvv[nt] = padv[nt * 16 + l16];

    // scores + online softmax; QE gathered by ONE shuffle (select at source).
    float s[4][4], mx[4];
#pragma unroll
    for (int r = 0; r < 4; r++) {
      int rloc = wave * 16 + quad * 4 + r;
      int ig = i0 + rloc;
      int t = quad * 4 + r;
      int v = 63 - 16 * wave + l16 - t;
      int srcl = (lane & 48) | (v & 15);
      bool hiSrc = (l16 < 15 - t);     // target hi <=> this at source lane
#pragma unroll
      for (int nt = 0; nt < 4; nt++) {
        float pre = hiSrc ? qef[nt + 1][r] : qef[nt][r];
        float qe = __shfl(pre, srcl);
        int jl = nt * 16 + l16;
        float sv = (sc[nt][r] + qe) * 0.125f + pvv[nt];
        if (j0 + jl > ig) sv = -1e30f;
        s[nt][r] = sv;
      }
      float m = fmaxf(fmaxf(s[0][r], s[1][r]), fmaxf(s[2][r], s[3][r]));
      float tr;
      DPP_ROR(tr, m, 1); m = fmaxf(m, tr);
      DPP_ROR(tr, m, 2); m = fmaxf(m, tr);
      DPP_ROR(tr, m, 4); m = fmaxf(m, tr);
      DPP_ROR(tr, m, 8); m = fmaxf(m, tr);
      mx[r] = m;
    }
    float alpha[4];
#pragma unroll
    for (int r = 0; r < 4; r++) {
      float m_new = fmaxf(m_run[r], mx[r]);
      alpha[r] = __expf(m_run[r] - m_new);
      float psum = 0.f;
      int rloc = wave * 16 + quad * 4 + r;
#pragma unroll
      for (int nt = 0; nt < 4; nt++) {
        float p = __expf(s[nt][r] - m_new);
        Ps[rloc][(nt * 16 + l16) ^ PS_SWZ(rloc)] = f2b(p);
        psum += p;
      }
      float tr;
      DPP_ROR(tr, psum, 1); psum += tr;
      DPP_ROR(tr, psum, 2); psum += tr;
      DPP_ROR(tr, psum, 4); psum += tr;
      DPP_ROR(tr, psum, 8); psum += tr;
      l_run[r] = l_run[r] * alpha[r] + psum;
      m_run[r] = m_new;
    }
#pragma unroll
    for (int dt = 0; dt < 4; dt++)
#pragma unroll
      for (int r = 0; r < 4; r++) acc[dt][r] *= alpha[r];

    // P @ V  (Ps rows are wave-local; swizzled reads match swizzled writes)
    {
      int prow = wave * 16 + l16;
      int psw = PS_SWZ(prow);
      s8frag p0 = *(const s8frag*)&Ps[prow][(quad * 8) ^ psw];
      s8frag p1 = *(const s8frag*)&Ps[prow][(32 + quad * 8) ^ psw];
#pragma unroll
      for (int dt = 0; dt < 4; dt++) {
        s8frag v0 = *(const s8frag*)&Vt[dt * 16 + l16][quad * 8];
        s8frag v1 = *(const s8frag*)&Vt[dt * 16 + l16][32 + quad * 8];
        acc[dt] = __builtin_amdgcn_mfma_f32_16x16x32_bf16(p0, v0, acc[dt], 0, 0, 0);
        acc[dt] = __builtin_amdgcn_mfma_f32_16x16x32_bf16(p1, v1, acc[dt], 0, 0, 0);
      }
    }
  }

  // write partials (indexed by logical slot, not blockIdx)
#pragma unroll
  for (int r = 0; r < 4; r++) {
    int rloc = wave * 16 + quad * 4 + r;
    if (l16 == 0) {
      pstat[(size_t)slot * 128 + rloc]      = m_run[r];
      pstat[(size_t)slot * 128 + 64 + rloc] = l_run[r];
    }
#pragma unroll
    for (int dt = 0; dt < 4; dt++)
      pacc[(size_t)slot * 4096 + rloc * 64 + dt * 16 + l16] = f2b(acc[dt][r]);
  }
}

// ---------------------------------------------------------------------------
// Merge <=4 chunk partials per (b,h,q-tile); write O (bf16) into qb.
// ---------------------------------------------------------------------------
__global__ __launch_bounds__(256) void attn_combine(
    const bf16u* __restrict__ pacc, const float* __restrict__ pstat,
    bf16u* __restrict__ O)
{
  int bid = blockIdx.x;             // g*32 + it
  int g = bid >> 5, it = bid & 31;
  int b = g >> 3, h = g & 7;
  int i0 = it * 64;
  int nc = (it >> 3) + 1;
  int tid = threadIdx.x;
  int row = tid >> 2, ql = tid & 3;

  float m_tot = -1e30f;
  float mc[4], lc[4];
#pragma unroll
  for (int c = 0; c < 4; c++) {
    if (c < nc) {
      size_t pb = (size_t)(bid * 4 + c) * 128;
      mc[c] = pstat[pb + row];
      lc[c] = pstat[pb + 64 + row];
      m_tot = fmaxf(m_tot, mc[c]);
    }
  }
  float l_tot = 0.f, w[4];
#pragma unroll
  for (int c = 0; c < 4; c++) {
    if (c < nc) { w[c] = __expf(mc[c] - m_tot); l_tot += w[c] * lc[c]; }
    else w[c] = 0.f;
  }
  float inv = 1.0f / l_tot;

  float out[16];
#pragma unroll
  for (int k = 0; k < 16; k++) out[k] = 0.f;
#pragma unroll
  for (int c = 0; c < 4; c++) {
    if (c >= nc) break;
    const bf16u* pa = pacc + (size_t)(bid * 4 + c) * 4096 + row * 64 + ql * 16;
#pragma unroll
    for (int k = 0; k < 16; k++) out[k] += w[c] * b2f(pa[k]);
  }
  bf16u* ob = O + ((size_t)(b * SEQ + i0 + row)) * DMODEL + h * DHEAD + ql * 16;
#pragma unroll
  for (int k = 0; k < 16; k++) ob[k] = f2b(out[k] * inv);
}

// ---------------------------------------------------------------------------
extern "C" void kernel_launch(void* const* d_in, const int* in_sizes, int n_in,
                              void* d_out, int out_size, void* d_ws, size_t ws_size,
                              hipStream_t stream) {
  const int*   toks  = (const int*)  d_in[0];
  const float* conds = (const float*)d_in[1];
  const float* ttc   = (const float*)d_in[2];
  const float* emb   = (const float*)d_in[3];
  const float* pos   = (const float*)d_in[4];
  const float* cW1   = (const float*)d_in[5];
  const float* cb1   = (const float*)d_in[6];
  const float* cW2   = (const float*)d_in[7];
  const float* cb2   = (const float*)d_in[8];
  const float* nullc = (const float*)d_in[9];
  const float* ttcW  = (const float*)d_in[10];
  const float* ttcb  = (const float*)d_in[11];
  const float* Wq    = (const float*)d_in[12];
  const float* Wk    = (const float*)d_in[13];
  const float* Wv    = (const float*)d_in[14];
  const float* Wo    = (const float*)d_in[15];
  const float* bq    = (const float*)d_in[16];
  const float* bk    = (const float*)d_in[17];
  const float* bv    = (const float*)d_in[18];
  const float* bo    = (const float*)d_in[19];
  const float* E     = (const float*)d_in[20];
  const float* fW1   = (const float*)d_in[21];
  const float* fb1   = (const float*)d_in[22];
  const float* fW2   = (const float*)d_in[23];
  const float* fb2   = (const float*)d_in[24];
  const float* ln1g  = (const float*)d_in[25];
  const float* ln1b  = (const float*)d_in[26];
  const float* ln2g  = (const float*)d_in[27];
  const float* ln2b  = (const float*)d_in[28];
  const float* fcW   = (const float*)d_in[29];
  const float* fcb   = (const float*)d_in[30];

  const size_t MB1 = 1024 * 1024;
  const size_t MD = (size_t)MROWS * DMODEL;
  char* p = (char*)d_ws;
  bf16u* xb    = (bf16u*)p; p += 4 * MB1;
  bf16u* qkvb  = (bf16u*)p; p += 12 * MB1;   // qb | kb | vb
  bf16u* hidb  = (bf16u*)p; p += 16 * MB1;   // FFN hidden / pacc alias
  float* pstat = (float*)p; p += 1 * MB1;
  bf16u* vbt   = (bf16u*)p; p += 4 * MB1;    // V transposed
  bf16u* ebf   = (bf16u*)p; p += 1536 * 1024;   // E bf16, 6 layers
  bf16u* WqkvT = (bf16u*)p; p += 9 * MB1;
  bf16u* WoT   = (bf16u*)p; p += 3 * MB1;
  bf16u* W1T   = (bf16u*)p; p += 12 * MB1;
  bf16u* W2T   = (bf16u*)p; p += 12 * MB1;
  bf16u* fcT   = (bf16u*)p; p += 512 * 1024;    // total 75 MB
  bf16u* qb = qkvb;
  bf16u* kb = qkvb + MD;        // out1b aliases kb (disjoint lifetimes)
  bf16u* vb = qkvb + 2 * MD;    // t1b aliases vb (disjoint lifetimes)
  bf16u* out1b = kb;
  bf16u* t1b   = vb;
  bf16u* pacc  = hidb;

  // ---- setup: embeds + all-layer weight transposes + E conversion ----
  cond_embed_kernel<<<dim3(NCOND, BATCH), 256, 0, stream>>>(
      conds, cW1, cb1, cW2, cb2, nullc, pos, xb);
  tok_embed_kernel<<<dim3(S_TOK, BATCH), 256, 0, stream>>>(toks, emb, pos, xb);
  wt_all_kernel<<<6 * 768 + 64, 256, 0, stream>>>(Wq, Wk, Wv, Wo, fW1, fW2, fcW,
      WqkvT, WoT, W1T, W2T, fcT);
  e_conv_kernel<<<(NLAYER * SEQ * DHEAD) / 1024, 256, 0, stream>>>(E, ebf);

  dim3 gQKV(MROWS / 128, 1536 / 128);      // (32,12)
  dim3 gFF1(MROWS / 128, DINNER / 128);    // (32,16)
  dim3 gN512(MROWS / 32, DMODEL / 128);    // (128,4): 512 blocks, RB=1

  for (int l = 0; l < NLAYER; l++) {
    // fused QKV
    mgemm<4><<<gQKV, 256, 0, stream>>>(xb, WqkvT + (size_t)l * 786432,
        bq + l * DMODEL, bk + l * DMODEL, bv + l * DMODEL, nullptr,
        nullptr, qkvb, MROWS, 1536, DMODEL, 4, nullptr, nullptr, nullptr);

    vt_kernel<<<512, 256, 0, stream>>>(vb, vbt);
    attn_part<<<2048, 256, 0, stream>>>(qb, kb, vbt,
        ebf + (size_t)l * SEQ * DHEAD, toks, pacc, pstat);
    attn_combine<<<512, 256, 0, stream>>>(pacc, pstat, qb);

    // t1 = attn @ Wo + bo + x
    mgemm<1><<<gN512, 256, 0, stream>>>(qb, WoT + (size_t)l * 262144,
        bo + l * DMODEL, nullptr, nullptr, xb,
        nullptr, t1b, MROWS, DMODEL, DMODEL, 1, nullptr, nullptr, nullptr);
    ln_kernel<<<MROWS, 256, 0, stream>>>(t1b, ln1g + l * DMODEL, ln1b + l * DMODEL,
        out1b);

    // hid = relu(out1 @ W1 + b1) + chord
    mgemm<4><<<gFF1, 256, 0, stream>>>(out1b, W1T + (size_t)l * 1048576,
        fb1 + l * DINNER, nullptr, nullptr, nullptr,
        nullptr, hidb, MROWS, DINNER, DMODEL, 2, ttc, ttcW, ttcb);
    // t1 = hid @ W2 + b2 + out1
    mgemm<1><<<gN512, 256, 0, stream>>>(hidb, W2T + (size_t)l * 1048576,
        fb2 + l * DMODEL, nullptr, nullptr, out1b,
        nullptr, t1b, MROWS, DMODEL, DINNER, 1, nullptr, nullptr, nullptr);
    ln_kernel<<<MROWS, 256, 0, stream>>>(t1b, ln2g + l * DMODEL, ln2b + l * DMODEL,
        xb);
  }

  // logits = x @ fc_W + fc_b (fp32 out)
  mgemm<1><<<gN512, 256, 0, stream>>>(xb, fcT,
      fcb, nullptr, nullptr, nullptr,
      (float*)d_out, nullptr, MROWS, VOCAB, DMODEL, 3, nullptr, nullptr, nullptr);
}